// Round 21
// baseline (515.947 us; speedup 1.0000x reference)
//
#include <hip/hip_runtime.h>
#include <hip/hip_bf16.h>
#include <math.h>

#define DIM   384
#define HEADS 12
#define HD    32
#define WIN   7
#define NPIX  49
#define IMG   56
#define NPF   3136
#define NWIN  1024
#define GB    4          // batches per group
#define NGRP  4

typedef __attribute__((ext_vector_type(8))) short short8;
typedef __attribute__((ext_vector_type(4))) float f32x4;
typedef __attribute__((ext_vector_type(4))) float f4;
typedef __attribute__((ext_vector_type(4))) unsigned short us4;
typedef __attribute__((ext_vector_type(8))) unsigned short us8;
#define MFMA __builtin_amdgcn_mfma_f32_16x16x32_bf16

#define SOFT_BARRIER()                                         \
  do {                                                         \
    asm volatile("s_waitcnt lgkmcnt(0)" ::: "memory");         \
    __builtin_amdgcn_s_barrier();                              \
  } while (0)

__device__ inline ushort tob(float f) {
  unsigned u; __builtin_memcpy(&u, &f, 4);
  u += 0x7fffu + ((u >> 16) & 1u);
  return (ushort)(u >> 16);
}

// bijective XCD swizzle for arbitrary nwg (m204 form)
__device__ inline int xcd_swz(int bid, int nwg) {
  int xcd = bid & 7, j = bid >> 3;
  int q = nwg >> 3, r = nwg & 7;
  int base = (xcd < r) ? xcd * (q + 1) : r * (q + 1) + (xcd - r) * q;
  return base + j;
}

// ---------------- bias table ----------------
__global__ void k_bias(const float* __restrict__ cpb, float* __restrict__ bias) {
  int idx = blockIdx.x * 256 + threadIdx.x;
  if (idx >= HEADS * NPIX * NPIX) return;
  int m = idx % NPIX;
  int n = (idx / NPIX) % NPIX;
  int h = idx / (NPIX * NPIX);
  int sy = (n / WIN - m / WIN) + (WIN - 1);
  int sx = (n % WIN - m % WIN) + (WIN - 1);
  const double inv_log_beta = 1.0 / log(1.3);
  double fy = (sy == 0 ? 0.0 : log1p((double)sy) * inv_log_beta) + 6.0;
  double fx = (sx == 0 ? 0.0 : log1p((double)sx) * inv_log_beta) + 6.0;
  fy = fmin(12.0, fmax(0.0, fy));
  fx = fmin(12.0, fmax(0.0, fx));
  int ridx = (int)(fy * 13.0 + fx);
  bias[idx] = cpb[ridx * HEADS + h];
}

__global__ void k_rmap(int* __restrict__ rmap) {
  int p = blockIdx.x * 256 + threadIdx.x;
  if (p < NPF) {
    int wb = p / NPIX, n = p - (p / NPIX) * NPIX;
    int gy = wb >> 3, gx = wb & 7;
    int wy = n / WIN, wx = n - (n / WIN) * WIN;
    rmap[p] = ((gy * WIN + wy + 4) % IMG) * IMG + (gx * WIN + wx + 4) % IMG;
  }
}

// ---------------- weights -> bf16 (once) ----------------
__global__ void k_wcvt(const float* __restrict__ wqkv, const float* __restrict__ wproj,
                       ushort* __restrict__ wqb, ushort* __restrict__ wpb) {
  int i = blockIdx.x * 256 + threadIdx.x;
  const int nq = 1152 * DIM / 8;
  const int np = DIM * DIM / 8;
  if (i < nq) {
    f4 a = *(const f4*)&wqkv[i * 8];
    f4 b = *(const f4*)&wqkv[i * 8 + 4];
    us8 u; u[0]=tob(a[0]);u[1]=tob(a[1]);u[2]=tob(a[2]);u[3]=tob(a[3]);
    u[4]=tob(b[0]);u[5]=tob(b[1]);u[6]=tob(b[2]);u[7]=tob(b[3]);
    *(us8*)&wqb[i * 8] = u;
  } else if (i < nq + np) {
    int j = i - nq;
    f4 a = *(const f4*)&wproj[j * 8];
    f4 b = *(const f4*)&wproj[j * 8 + 4];
    us8 u; u[0]=tob(a[0]);u[1]=tob(a[1]);u[2]=tob(a[2]);u[3]=tob(a[3]);
    u[4]=tob(b[0]);u[5]=tob(b[1]);u[6]=tob(b[2]);u[7]=tob(b[3]);
    *(us8*)&wpb[j * 8] = u;
  }
}

// ---------------- x -> xw (per batch group) ----------------
__global__ __launch_bounds__(256) void k_xw(const float* __restrict__ x,
                                            const int* __restrict__ rmap,
                                            ushort* __restrict__ xw, int b0) {
  int gid = blockIdx.x * 256 + threadIdx.x;   // GB*3136 exact
  int b = b0 + gid / NPF, p = gid % NPF;
  int sp = rmap[p];
  const float* xs = x + (size_t)b * DIM * NPF + sp;
  ushort* xd = xw + ((size_t)b * NPF + p) * DIM;
  for (int c0 = 0; c0 < DIM; c0 += 8) {
    us8 u;
#pragma unroll
    for (int i = 0; i < 8; ++i) u[i] = tob(xs[(size_t)(c0 + i) * NPF]);
    *(us8*)&xd[c0] = u;
  }
}

// ---------------- QKV GEMM (per group): 2-ahead staging + soft barriers -----
__global__ __launch_bounds__(256) void k_qkv_pm(const ushort* __restrict__ xw,
                                                const ushort* __restrict__ wqb,
                                                ushort* __restrict__ qkv, int b0) {
  __shared__ __align__(16) ushort sA[2][128 * 40];
  __shared__ __align__(16) ushort sB[2][256 * 40];
  int t   = threadIdx.x;
  const int nwg = 9 * 13 * GB;
  int swz = xcd_swz(blockIdx.x, nwg);
  int o0  = (swz % 9) * 128;
  int pbt = swz / 9;
  int p0  = (pbt % 13) * 256;
  int b   = b0 + pbt / 13;

  int lane = t & 63, w = t >> 6;
  int wm = w >> 1, wn = w & 1;
  int l15 = lane & 15, l4 = lane >> 4;

  int arow = t & 127, ash = (t >> 7) * 16;
  const ushort* apt = wqb + (size_t)(o0 + arow) * DIM + ash;
  int brow = t;
  int prow = p0 + brow; if (prow >= NPF) prow = NPF - 1;
  const ushort* bpt = xw + ((size_t)b * NPF + prow) * DIM;

  struct Stage { us8 a0, a1, b0, b1, b2, b3; };
  Stage st0, st1;

#define QLOAD(S, K0)                                    \
  do {                                                  \
    (S).a0 = *(const us8*)&apt[(K0)];                   \
    (S).a1 = *(const us8*)&apt[(K0) + 8];               \
    (S).b0 = *(const us8*)&bpt[(K0)];                   \
    (S).b1 = *(const us8*)&bpt[(K0) + 8];               \
    (S).b2 = *(const us8*)&bpt[(K0) + 16];              \
    (S).b3 = *(const us8*)&bpt[(K0) + 24];              \
  } while (0)
#define QWRITE(S, BUF)                                  \
  do {                                                  \
    *(us8*)&sA[(BUF)][arow * 40 + ash]     = (S).a0;    \
    *(us8*)&sA[(BUF)][arow * 40 + ash + 8] = (S).a1;    \
    *(us8*)&sB[(BUF)][brow * 40]      = (S).b0;         \
    *(us8*)&sB[(BUF)][brow * 40 + 8]  = (S).b1;         \
    *(us8*)&sB[(BUF)][brow * 40 + 16] = (S).b2;         \
    *(us8*)&sB[(BUF)][brow * 40 + 24] = (S).b3;         \
  } while (0)

  f32x4 acc[4][8] = {};

  QLOAD(st0, 0);
  QWRITE(st0, 0);
  QLOAD(st1, 32);

#pragma unroll
  for (int ks = 0; ks < 12; ++ks) {
    SOFT_BARRIER();
    if (ks < 10) {
      if ((ks & 1) == 0) QLOAD(st0, (ks + 2) * 32);
      else               QLOAD(st1, (ks + 2) * 32);
    }
    int cur = ks & 1;
    short8 af[4], bfr[8];
#pragma unroll
    for (int mi = 0; mi < 4; ++mi)
      af[mi] = *(const short8*)&sA[cur][(wm * 64 + mi * 16 + l15) * 40 + l4 * 8];
#pragma unroll
    for (int ni = 0; ni < 8; ++ni)
      bfr[ni] = *(const short8*)&sB[cur][(wn * 128 + ni * 16 + l15) * 40 + l4 * 8];
#pragma unroll
    for (int mi = 0; mi < 4; ++mi)
#pragma unroll
      for (int ni = 0; ni < 8; ++ni)
        acc[mi][ni] = MFMA(af[mi], bfr[ni], acc[mi][ni], 0, 0, 0);
    if (ks < 11) {
      if ((ks & 1) == 0) QWRITE(st1, 1);
      else               QWRITE(st0, 0);
    }
  }
#undef QLOAD
#undef QWRITE

#pragma unroll
  for (int mi = 0; mi < 4; ++mi)
#pragma unroll
    for (int ni = 0; ni < 8; ++ni) {
      int p = p0 + wn * 128 + ni * 16 + l15;
      if (p < NPF) {
        us4 u;
#pragma unroll
        for (int r = 0; r < 4; ++r) u[r] = tob(acc[mi][ni][r]);
        *(us4*)&qkv[((size_t)b * NPF + p) * 1152 + o0 + wm * 64 + mi * 16 + (l4 << 2)] = u;
      }
    }
}

// ---------------- attention (per group) ----------------
__global__ __launch_bounds__(64) void k_attn_pm(ushort* __restrict__ qkv,
                                                const float* __restrict__ bias, int b0) {
  __shared__ __align__(16) ushort smem[8992];
  ushort* sq  = smem;          // [64][40]
  ushort* skt = smem + 2560;   // [64][40]
  ushort* svt = smem + 5120;   // [32][72]
  ushort* stg = smem + 7424;   // [49][32]
  ushort* pa  = smem;          // [64][72] overlays sq/skt

  int t = threadIdx.x;
  const int nwg = GB * 64 * HEADS;
  int swz = xcd_swz(blockIdx.x, nwg);
  int h = swz % HEADS;
  int wbl = swz / HEADS;
  int b = b0 + (wbl >> 6);
  int w49 = (wbl & 63) * NPIX;
  ushort* qrow = qkv + ((size_t)b * NPF + w49) * 1152 + h * HD;

  for (int idx = t; idx < 32 * 23; idx += 64) {
    int d = idx / 23, mm = 49 + (idx - (idx / 23) * 23);
    svt[d * 72 + mm] = 0;
  }
  for (int idx = t; idx < NPIX * 4; idx += 64) {
    int n = idx >> 2, s = (idx & 3) * 8;
    *(us8*)&sq [n * 40 + s] = *(const us8*)&qrow[(size_t)n * 1152 + s];
    *(us8*)&skt[n * 40 + s] = *(const us8*)&qrow[(size_t)n * 1152 + DIM + s];
    *(us8*)&stg[n * 32 + s] = *(const us8*)&qrow[(size_t)n * 1152 + 2 * DIM + s];
  }
  __syncthreads();
  for (int idx = t; idx < HD * NPIX; idx += 64) {
    int d = idx / NPIX, m = idx - d * NPIX;
    svt[d * 72 + m] = stg[m * 32 + d];
  }
  __syncthreads();

  int l15 = t & 15, l4 = t >> 4;
  f32x4 acc[4][4] = {};
  {
    short8 af[4], bfr[4];
#pragma unroll
    for (int mi = 0; mi < 4; ++mi) af[mi]  = *(const short8*)&sq [(mi * 16 + l15) * 40 + l4 * 8];
#pragma unroll
    for (int ni = 0; ni < 4; ++ni) bfr[ni] = *(const short8*)&skt[(ni * 16 + l15) * 40 + l4 * 8];
#pragma unroll
    for (int mi = 0; mi < 4; ++mi)
#pragma unroll
      for (int ni = 0; ni < 4; ++ni)
        acc[mi][ni] = MFMA(af[mi], bfr[ni], acc[mi][ni], 0, 0, 0);
  }

  const float scale = 0.17677669529663687f;
  const float* bh = bias + h * NPIX * NPIX;
  float mx[16], sm[16];
#pragma unroll
  for (int mi = 0; mi < 4; ++mi)
#pragma unroll
    for (int r = 0; r < 4; ++r) {
      int n = mi * 16 + (l4 << 2) + r;
      float vmax = -3e38f;
#pragma unroll
      for (int ni = 0; ni < 4; ++ni) {
        int m = ni * 16 + l15;
        float s = (m < NPIX)
                    ? acc[mi][ni][r] * scale + ((n < NPIX) ? bh[n * NPIX + m] : 0.f)
                    : -3e38f;
        acc[mi][ni][r] = s;
        vmax = fmaxf(vmax, s);
      }
      mx[mi * 4 + r] = vmax;
    }
#pragma unroll
  for (int i = 1; i < 16; i <<= 1)
#pragma unroll
    for (int j = 0; j < 16; ++j) mx[j] = fmaxf(mx[j], __shfl_xor(mx[j], i));
#pragma unroll
  for (int mi = 0; mi < 4; ++mi)
#pragma unroll
    for (int r = 0; r < 4; ++r) {
      float s = 0.f;
#pragma unroll
      for (int ni = 0; ni < 4; ++ni) {
        float e = expf(acc[mi][ni][r] - mx[mi * 4 + r]);
        acc[mi][ni][r] = e;
        s += e;
      }
      sm[mi * 4 + r] = s;
    }
#pragma unroll
  for (int i = 1; i < 16; i <<= 1)
#pragma unroll
    for (int j = 0; j < 16; ++j) sm[j] += __shfl_xor(sm[j], i);

  __syncthreads();
#pragma unroll
  for (int mi = 0; mi < 4; ++mi)
#pragma unroll
    for (int r = 0; r < 4; ++r) {
      float ri = 1.f / sm[mi * 4 + r];
      int n = mi * 16 + (l4 << 2) + r;
#pragma unroll
      for (int ni = 0; ni < 4; ++ni)
        pa[n * 72 + ni * 16 + l15] = tob(acc[mi][ni][r] * ri);
    }
  __syncthreads();

  f32x4 yac[4][2] = {};
#pragma unroll
  for (int ks = 0; ks < 2; ++ks) {
    short8 pf[4], vf[2];
#pragma unroll
    for (int mi = 0; mi < 4; ++mi) pf[mi] = *(const short8*)&pa [(mi * 16 + l15) * 72 + ks * 32 + l4 * 8];
#pragma unroll
    for (int nd = 0; nd < 2; ++nd) vf[nd] = *(const short8*)&svt[(nd * 16 + l15) * 72 + ks * 32 + l4 * 8];
#pragma unroll
    for (int mi = 0; mi < 4; ++mi)
#pragma unroll
      for (int nd = 0; nd < 2; ++nd)
        yac[mi][nd] = MFMA(pf[mi], vf[nd], yac[mi][nd], 0, 0, 0);
  }
#pragma unroll
  for (int mi = 0; mi < 4; ++mi)
#pragma unroll
    for (int nd = 0; nd < 2; ++nd) {
      int nb = mi * 16 + (l4 << 2);
      int d = nd * 16 + l15;
#pragma unroll
      for (int r = 0; r < 4; ++r)
        if (nb + r < NPIX) qrow[(size_t)(nb + r) * 1152 + d] = tob(yac[mi][nd][r]);
    }
}

// ---------------- proj GEMM (per group) ----------------
__global__ __launch_bounds__(256) void k_proj_pm(const ushort* __restrict__ qkv,
                                                 const ushort* __restrict__ wpb,
                                                 float* __restrict__ out, int b0) {
  __shared__ __align__(16) ushort sA[2][128 * 40];
  __shared__ __align__(16) ushort sB[2][128 * 40];
  __shared__ int srm[128];
  int t   = threadIdx.x;
  const int nwg = 3 * 25 * GB;
  int swz = xcd_swz(blockIdx.x, nwg);
  int o0  = (swz % 3) * 128;
  int pb  = swz / 3;
  int p0  = (pb % 25) * 128;
  int b   = b0 + pb / 25;
  if (t < 128) {
    int pg = p0 + t;
    if (pg >= NPF) pg = 0;
    int si = (pg / IMG + 53) % IMG, sj = (pg % IMG + 53) % IMG;
    srm[t] = ((si / WIN) * 8 + sj / WIN) * NPIX + (si % WIN) * WIN + (sj % WIN);
  }
  __syncthreads();

  int lane = t & 63, w = t >> 6;
  int wm = w >> 1, wn = w & 1;
  int l15 = lane & 15, l4 = lane >> 4;

  int row = t & 127, sh = (t >> 7) * 16;
  const ushort* apt = wpb + (size_t)(o0 + row) * DIM;
  const ushort* bpt = qkv + ((size_t)b * NPF + srm[row]) * 1152;

  struct Stage { us8 a0, a1, b0, b1; };
  Stage st0, st1;

#define PLOAD(S, K0)                                    \
  do {                                                  \
    (S).a0 = *(const us8*)&apt[(K0) + sh];              \
    (S).a1 = *(const us8*)&apt[(K0) + sh + 8];          \
    (S).b0 = *(const us8*)&bpt[(K0) + sh];              \
    (S).b1 = *(const us8*)&bpt[(K0) + sh + 8];          \
  } while (0)
#define PWRITE(S, BUF)                                  \
  do {                                                  \
    *(us8*)&sA[(BUF)][row * 40 + sh]     = (S).a0;      \
    *(us8*)&sA[(BUF)][row * 40 + sh + 8] = (S).a1;      \
    *(us8*)&sB[(BUF)][row * 40 + sh]     = (S).b0;      \
    *(us8*)&sB[(BUF)][row * 40 + sh + 8] = (S).b1;      \
  } while (0)

  f32x4 acc[4][4] = {};

  PLOAD(st0, 0);
  PWRITE(st0, 0);
  PLOAD(st1, 32);

#pragma unroll
  for (int ks = 0; ks < 12; ++ks) {
    SOFT_BARRIER();
    if (ks < 10) {
      if ((ks & 1) == 0) PLOAD(st0, (ks + 2) * 32);
      else               PLOAD(st1, (ks + 2) * 32);
    }
    int cur = ks & 1;
    short8 af[4], bfr[4];
#pragma unroll
    for (int mi = 0; mi < 4; ++mi)
      af[mi] = *(const short8*)&sA[cur][(wm * 64 + mi * 16 + l15) * 40 + l4 * 8];
#pragma unroll
    for (int ni = 0; ni < 4; ++ni)
      bfr[ni] = *(const short8*)&sB[cur][(wn * 64 + ni * 16 + l15) * 40 + l4 * 8];
#pragma unroll
    for (int mi = 0; mi < 4; ++mi)
#pragma unroll
      for (int ni = 0; ni < 4; ++ni)
        acc[mi][ni] = MFMA(af[mi], bfr[ni], acc[mi][ni], 0, 0, 0);
    if (ks < 11) {
      if ((ks & 1) == 0) PWRITE(st1, 1);
      else               PWRITE(st0, 0);
    }
  }
#undef PLOAD
#undef PWRITE

  for (int mi = 0; mi < 4; ++mi)
    for (int ni = 0; ni < 4; ++ni)
      for (int r = 0; r < 4; ++r) {
        int o = o0 + wm * 64 + mi * 16 + (l4 << 2) + r;
        int p = p0 + wn * 64 + ni * 16 + l15;
        if (p < NPF)
          out[((size_t)b * DIM + o) * NPF + p] = acc[mi][ni][r];
      }
}

extern "C" void kernel_launch(void* const* d_in, const int* in_sizes, int n_in,
                              void* d_out, int out_size, void* d_ws, size_t ws_size,
                              hipStream_t stream) {
  const float* x     = (const float*)d_in[0];
  const float* wqkv  = (const float*)d_in[1];
  const float* wproj = (const float*)d_in[2];
  const float* cpb   = (const float*)d_in[3];
  float* out = (float*)d_out;

  char* ws = (char*)d_ws;
  float* bias = (float*)ws;                       // 115248 B
  int*   rmap = (int*)(ws + 115712);              // -> 131072
  ushort* wqb = (ushort*)(ws + 131072);           // 884736 B
  ushort* wpb = (ushort*)(ws + 1015808);          // 294912 B -> 1310720
  const size_t QKV_B = (size_t)16 * 1152 * NPF * 2;   // 115.6 MB
  ushort* qkv = (ushort*)(ws + 1310720);
  ushort* xw  = (ushort*)(ws + 1310720 + QKV_B);      // 38.5 MB (ws >= 155.5 MB proven)

  hipLaunchKernelGGL(k_bias, dim3(113), dim3(256), 0, stream, cpb, bias);
  hipLaunchKernelGGL(k_rmap, dim3(13), dim3(256), 0, stream, rmap);
  hipLaunchKernelGGL(k_wcvt, dim3(288), dim3(256), 0, stream, wqkv, wproj, wqb, wpb);

  for (int g = 0; g < NGRP; ++g) {
    int b0 = g * GB;
    hipLaunchKernelGGL(k_xw, dim3(GB * NPF / 256), dim3(256), 0, stream, x, rmap, xw, b0);
    hipLaunchKernelGGL(k_qkv_pm, dim3(9 * 13 * GB), dim3(256), 0, stream, xw, wqb, qkv, b0);
    hipLaunchKernelGGL(k_attn_pm, dim3(GB * 64 * HEADS), dim3(64), 0, stream, qkv, bias, b0);
    hipLaunchKernelGGL(k_proj_pm, dim3(3 * 25 * GB), dim3(256), 0, stream, qkv, wpb, out, b0);
  }
}

// Round 22
// 286.432 us; speedup vs baseline: 1.8013x; 1.8013x over previous
//
#include <hip/hip_runtime.h>
#include <hip/hip_bf16.h>
#include <math.h>

#define DIM   384
#define HEADS 12
#define HD    32
#define WIN   7
#define NPIX  49
#define IMG   56
#define NPF   3136
#define NWIN  1024

typedef __attribute__((ext_vector_type(8))) short short8;
typedef __attribute__((ext_vector_type(4))) float f32x4;
typedef __attribute__((ext_vector_type(4))) float f4;
typedef __attribute__((ext_vector_type(4))) unsigned short us4;
typedef __attribute__((ext_vector_type(8))) unsigned short us8;
#define MFMA __builtin_amdgcn_mfma_f32_16x16x32_bf16

#define SOFT_BARRIER()                                         \
  do {                                                         \
    asm volatile("s_waitcnt lgkmcnt(0)" ::: "memory");         \
    __builtin_amdgcn_s_barrier();                              \
  } while (0)

__device__ inline ushort tob(float f) {
  unsigned u; __builtin_memcpy(&u, &f, 4);
  u += 0x7fffu + ((u >> 16) & 1u);
  return (ushort)(u >> 16);
}

// ---------------- bias table ----------------
__global__ void k_bias(const float* __restrict__ cpb, float* __restrict__ bias) {
  int idx = blockIdx.x * 256 + threadIdx.x;
  if (idx >= HEADS * NPIX * NPIX) return;
  int m = idx % NPIX;
  int n = (idx / NPIX) % NPIX;
  int h = idx / (NPIX * NPIX);
  int sy = (n / WIN - m / WIN) + (WIN - 1);
  int sx = (n % WIN - m % WIN) + (WIN - 1);
  const double inv_log_beta = 1.0 / log(1.3);
  double fy = (sy == 0 ? 0.0 : log1p((double)sy) * inv_log_beta) + 6.0;
  double fx = (sx == 0 ? 0.0 : log1p((double)sx) * inv_log_beta) + 6.0;
  fy = fmin(12.0, fmax(0.0, fy));
  fx = fmin(12.0, fmax(0.0, fx));
  int ridx = (int)(fy * 13.0 + fx);
  bias[idx] = cpb[ridx * HEADS + h];
}

__global__ void k_rmap(int* __restrict__ rmap) {
  int p = blockIdx.x * 256 + threadIdx.x;
  if (p < NPF) {
    int wb = p / NPIX, n = p - (p / NPIX) * NPIX;
    int gy = wb >> 3, gx = wb & 7;
    int wy = n / WIN, wx = n - (n / WIN) * WIN;
    rmap[p] = ((gy * WIN + wy + 4) % IMG) * IMG + (gx * WIN + wx + 4) % IMG;
  }
}

// ---------------- weights -> bf16 (once) ----------------
__global__ void k_wcvt(const float* __restrict__ wqkv, const float* __restrict__ wproj,
                       ushort* __restrict__ wqb, ushort* __restrict__ wpb) {
  int i = blockIdx.x * 256 + threadIdx.x;
  const int nq = 1152 * DIM / 8;
  const int np = DIM * DIM / 8;
  if (i < nq) {
    f4 a = *(const f4*)&wqkv[i * 8];
    f4 b = *(const f4*)&wqkv[i * 8 + 4];
    us8 u; u[0]=tob(a[0]);u[1]=tob(a[1]);u[2]=tob(a[2]);u[3]=tob(a[3]);
    u[4]=tob(b[0]);u[5]=tob(b[1]);u[6]=tob(b[2]);u[7]=tob(b[3]);
    *(us8*)&wqb[i * 8] = u;
  } else if (i < nq + np) {
    int j = i - nq;
    f4 a = *(const f4*)&wproj[j * 8];
    f4 b = *(const f4*)&wproj[j * 8 + 4];
    us8 u; u[0]=tob(a[0]);u[1]=tob(a[1]);u[2]=tob(a[2]);u[3]=tob(a[3]);
    u[4]=tob(b[0]);u[5]=tob(b[1]);u[6]=tob(b[2]);u[7]=tob(b[3]);
    *(us8*)&wpb[j * 8] = u;
  }
}

// ---------------- x -> xw[b][p'][c] bf16, 6-way channel-split for occupancy -
// grid 1176 blocks (4.6/CU): thread = (b, cc, p) with p fastest (coalesced).
__global__ __launch_bounds__(256) void k_xw(const float* __restrict__ x,
                                            const int* __restrict__ rmap,
                                            ushort* __restrict__ xw) {
  int gid = blockIdx.x * 256 + threadIdx.x;   // 16*6*3136 exact
  int p  = gid % NPF;
  int cc = (gid / NPF) % 6;
  int b  = gid / (6 * NPF);
  int sp = rmap[p];
  const float* xs = x + (size_t)b * DIM * NPF + (size_t)(cc * 64) * NPF + sp;
  ushort* xd = xw + ((size_t)b * NPF + p) * DIM + cc * 64;
  for (int c0 = 0; c0 < 64; c0 += 8) {
    us8 u;
#pragma unroll
    for (int i = 0; i < 8; ++i) u[i] = tob(xs[(size_t)(c0 + i) * NPF]);
    *(us8*)&xd[c0] = u;
  }
}

// ---------------- QKV GEMM: 2-ahead staging + soft barriers (r20) -----------
__global__ __launch_bounds__(256) void k_qkv_pm(const ushort* __restrict__ xw,
                                                const ushort* __restrict__ wqb,
                                                ushort* __restrict__ qkv) {
  __shared__ __align__(16) ushort sA[2][128 * 40];
  __shared__ __align__(16) ushort sB[2][256 * 40];
  int t   = threadIdx.x;
  int bid = blockIdx.x;
  int swz = (bid & 7) * 234 + (bid >> 3);   // 1872 = 8*234, bijective
  int o0  = (swz % 9) * 128;
  int pbt = swz / 9;
  int p0  = (pbt % 13) * 256;
  int b   = pbt / 13;

  int lane = t & 63, w = t >> 6;
  int wm = w >> 1, wn = w & 1;
  int l15 = lane & 15, l4 = lane >> 4;

  int arow = t & 127, ash = (t >> 7) * 16;
  const ushort* apt = wqb + (size_t)(o0 + arow) * DIM + ash;
  int brow = t;
  int prow = p0 + brow; if (prow >= NPF) prow = NPF - 1;
  const ushort* bpt = xw + ((size_t)b * NPF + prow) * DIM;

  struct Stage { us8 a0, a1, b0, b1, b2, b3; };
  Stage st0, st1;

#define QLOAD(S, K0)                                    \
  do {                                                  \
    (S).a0 = *(const us8*)&apt[(K0)];                   \
    (S).a1 = *(const us8*)&apt[(K0) + 8];               \
    (S).b0 = *(const us8*)&bpt[(K0)];                   \
    (S).b1 = *(const us8*)&bpt[(K0) + 8];               \
    (S).b2 = *(const us8*)&bpt[(K0) + 16];              \
    (S).b3 = *(const us8*)&bpt[(K0) + 24];              \
  } while (0)
#define QWRITE(S, BUF)                                  \
  do {                                                  \
    *(us8*)&sA[(BUF)][arow * 40 + ash]     = (S).a0;    \
    *(us8*)&sA[(BUF)][arow * 40 + ash + 8] = (S).a1;    \
    *(us8*)&sB[(BUF)][brow * 40]      = (S).b0;         \
    *(us8*)&sB[(BUF)][brow * 40 + 8]  = (S).b1;         \
    *(us8*)&sB[(BUF)][brow * 40 + 16] = (S).b2;         \
    *(us8*)&sB[(BUF)][brow * 40 + 24] = (S).b3;         \
  } while (0)

  f32x4 acc[4][8] = {};

  QLOAD(st0, 0);
  QWRITE(st0, 0);
  QLOAD(st1, 32);

#pragma unroll
  for (int ks = 0; ks < 12; ++ks) {
    SOFT_BARRIER();
    if (ks < 10) {
      if ((ks & 1) == 0) QLOAD(st0, (ks + 2) * 32);
      else               QLOAD(st1, (ks + 2) * 32);
    }
    int cur = ks & 1;
    short8 af[4], bfr[8];
#pragma unroll
    for (int mi = 0; mi < 4; ++mi)
      af[mi] = *(const short8*)&sA[cur][(wm * 64 + mi * 16 + l15) * 40 + l4 * 8];
#pragma unroll
    for (int ni = 0; ni < 8; ++ni)
      bfr[ni] = *(const short8*)&sB[cur][(wn * 128 + ni * 16 + l15) * 40 + l4 * 8];
#pragma unroll
    for (int mi = 0; mi < 4; ++mi)
#pragma unroll
      for (int ni = 0; ni < 8; ++ni)
        acc[mi][ni] = MFMA(af[mi], bfr[ni], acc[mi][ni], 0, 0, 0);
    if (ks < 11) {
      if ((ks & 1) == 0) QWRITE(st1, 1);
      else               QWRITE(st0, 0);
    }
  }
#undef QLOAD
#undef QWRITE

#pragma unroll
  for (int mi = 0; mi < 4; ++mi)
#pragma unroll
    for (int ni = 0; ni < 8; ++ni) {
      int p = p0 + wn * 128 + ni * 16 + l15;
      if (p < NPF) {
        us4 u;
#pragma unroll
        for (int r = 0; r < 4; ++r) u[r] = tob(acc[mi][ni][r]);
        *(us4*)&qkv[((size_t)b * NPF + p) * 1152 + o0 + wm * 64 + mi * 16 + (l4 << 2)] = u;
      }
    }
}

// ---------------- attention (r12 verbatim) ----------------
__global__ __launch_bounds__(64) void k_attn_pm(ushort* __restrict__ qkv,
                                                const float* __restrict__ bias) {
  __shared__ __align__(16) ushort smem[8992];
  ushort* sq  = smem;          // [64][40]
  ushort* skt = smem + 2560;   // [64][40]
  ushort* svt = smem + 5120;   // [32][72]
  ushort* stg = smem + 7424;   // [49][32]
  ushort* pa  = smem;          // [64][72] overlays sq/skt

  int t = threadIdx.x;
  int bid = blockIdx.x;
  int swz = (bid & 7) * 1536 + (bid >> 3);   // 12288 = 8*1536
  int h = swz % HEADS, wb = swz / HEADS;
  int b = wb >> 6;
  int w49 = (wb & 63) * NPIX;
  ushort* qrow = qkv + ((size_t)b * NPF + w49) * 1152 + h * HD;

  for (int idx = t; idx < 32 * 23; idx += 64) {
    int d = idx / 23, mm = 49 + (idx - (idx / 23) * 23);
    svt[d * 72 + mm] = 0;
  }
  for (int idx = t; idx < NPIX * 4; idx += 64) {
    int n = idx >> 2, s = (idx & 3) * 8;
    *(us8*)&sq [n * 40 + s] = *(const us8*)&qrow[(size_t)n * 1152 + s];
    *(us8*)&skt[n * 40 + s] = *(const us8*)&qrow[(size_t)n * 1152 + DIM + s];
    *(us8*)&stg[n * 32 + s] = *(const us8*)&qrow[(size_t)n * 1152 + 2 * DIM + s];
  }
  __syncthreads();
  for (int idx = t; idx < HD * NPIX; idx += 64) {
    int d = idx / NPIX, m = idx - d * NPIX;
    svt[d * 72 + m] = stg[m * 32 + d];
  }
  __syncthreads();

  int l15 = t & 15, l4 = t >> 4;
  f32x4 acc[4][4] = {};
  {
    short8 af[4], bfr[4];
#pragma unroll
    for (int mi = 0; mi < 4; ++mi) af[mi]  = *(const short8*)&sq [(mi * 16 + l15) * 40 + l4 * 8];
#pragma unroll
    for (int ni = 0; ni < 4; ++ni) bfr[ni] = *(const short8*)&skt[(ni * 16 + l15) * 40 + l4 * 8];
#pragma unroll
    for (int mi = 0; mi < 4; ++mi)
#pragma unroll
      for (int ni = 0; ni < 4; ++ni)
        acc[mi][ni] = MFMA(af[mi], bfr[ni], acc[mi][ni], 0, 0, 0);
  }

  const float scale = 0.17677669529663687f;
  const float* bh = bias + h * NPIX * NPIX;
  float mx[16], sm[16];
#pragma unroll
  for (int mi = 0; mi < 4; ++mi)
#pragma unroll
    for (int r = 0; r < 4; ++r) {
      int n = mi * 16 + (l4 << 2) + r;
      float vmax = -3e38f;
#pragma unroll
      for (int ni = 0; ni < 4; ++ni) {
        int m = ni * 16 + l15;
        float s = (m < NPIX)
                    ? acc[mi][ni][r] * scale + ((n < NPIX) ? bh[n * NPIX + m] : 0.f)
                    : -3e38f;
        acc[mi][ni][r] = s;
        vmax = fmaxf(vmax, s);
      }
      mx[mi * 4 + r] = vmax;
    }
#pragma unroll
  for (int i = 1; i < 16; i <<= 1)
#pragma unroll
    for (int j = 0; j < 16; ++j) mx[j] = fmaxf(mx[j], __shfl_xor(mx[j], i));
#pragma unroll
  for (int mi = 0; mi < 4; ++mi)
#pragma unroll
    for (int r = 0; r < 4; ++r) {
      float s = 0.f;
#pragma unroll
      for (int ni = 0; ni < 4; ++ni) {
        float e = expf(acc[mi][ni][r] - mx[mi * 4 + r]);
        acc[mi][ni][r] = e;
        s += e;
      }
      sm[mi * 4 + r] = s;
    }
#pragma unroll
  for (int i = 1; i < 16; i <<= 1)
#pragma unroll
    for (int j = 0; j < 16; ++j) sm[j] += __shfl_xor(sm[j], i);

  __syncthreads();
#pragma unroll
  for (int mi = 0; mi < 4; ++mi)
#pragma unroll
    for (int r = 0; r < 4; ++r) {
      float ri = 1.f / sm[mi * 4 + r];
      int n = mi * 16 + (l4 << 2) + r;
#pragma unroll
      for (int ni = 0; ni < 4; ++ni)
        pa[n * 72 + ni * 16 + l15] = tob(acc[mi][ni][r] * ri);
    }
  __syncthreads();

  f32x4 yac[4][2] = {};
#pragma unroll
  for (int ks = 0; ks < 2; ++ks) {
    short8 pf[4], vf[2];
#pragma unroll
    for (int mi = 0; mi < 4; ++mi) pf[mi] = *(const short8*)&pa [(mi * 16 + l15) * 72 + ks * 32 + l4 * 8];
#pragma unroll
    for (int nd = 0; nd < 2; ++nd) vf[nd] = *(const short8*)&svt[(nd * 16 + l15) * 72 + ks * 32 + l4 * 8];
#pragma unroll
    for (int mi = 0; mi < 4; ++mi)
#pragma unroll
      for (int nd = 0; nd < 2; ++nd)
        yac[mi][nd] = MFMA(pf[mi], vf[nd], yac[mi][nd], 0, 0, 0);
  }
#pragma unroll
  for (int mi = 0; mi < 4; ++mi)
#pragma unroll
    for (int nd = 0; nd < 2; ++nd) {
      int nb = mi * 16 + (l4 << 2);
      int d = nd * 16 + l15;
#pragma unroll
      for (int r = 0; r < 4; ++r)
        if (nb + r < NPIX) qrow[(size_t)(nb + r) * 1152 + d] = tob(yac[mi][nd][r]);
    }
}

// ---------------- proj GEMM: 128x128 + 2-ahead staging + soft barriers ------
__global__ __launch_bounds__(256) void k_proj_pm(const ushort* __restrict__ qkv,
                                                 const ushort* __restrict__ wpb,
                                                 float* __restrict__ out) {
  __shared__ __align__(16) ushort sA[2][128 * 40];
  __shared__ __align__(16) ushort sB[2][128 * 40];
  __shared__ int srm[128];
  int t   = threadIdx.x;
  int bid = blockIdx.x;
  int swz = (bid & 7) * 150 + (bid >> 3);   // 1200 = 8*150
  int o0  = (swz % 3) * 128;
  int pb  = swz / 3;
  int p0  = (pb % 25) * 128;
  int b   = pb / 25;
  if (t < 128) {
    int pg = p0 + t;
    if (pg >= NPF) pg = 0;
    int si = (pg / IMG + 53) % IMG, sj = (pg % IMG + 53) % IMG;
    srm[t] = ((si / WIN) * 8 + sj / WIN) * NPIX + (si % WIN) * WIN + (sj % WIN);
  }
  __syncthreads();

  int lane = t & 63, w = t >> 6;
  int wm = w >> 1, wn = w & 1;
  int l15 = lane & 15, l4 = lane >> 4;

  int row = t & 127, sh = (t >> 7) * 16;
  const ushort* apt = wpb + (size_t)(o0 + row) * DIM;
  const ushort* bpt = qkv + ((size_t)b * NPF + srm[row]) * 1152;

  struct Stage { us8 a0, a1, b0, b1; };
  Stage st0, st1;

#define PLOAD(S, K0)                                    \
  do {                                                  \
    (S).a0 = *(const us8*)&apt[(K0) + sh];              \
    (S).a1 = *(const us8*)&apt[(K0) + sh + 8];          \
    (S).b0 = *(const us8*)&bpt[(K0) + sh];              \
    (S).b1 = *(const us8*)&bpt[(K0) + sh + 8];          \
  } while (0)
#define PWRITE(S, BUF)                                  \
  do {                                                  \
    *(us8*)&sA[(BUF)][row * 40 + sh]     = (S).a0;      \
    *(us8*)&sA[(BUF)][row * 40 + sh + 8] = (S).a1;      \
    *(us8*)&sB[(BUF)][row * 40 + sh]     = (S).b0;      \
    *(us8*)&sB[(BUF)][row * 40 + sh + 8] = (S).b1;      \
  } while (0)

  f32x4 acc[4][4] = {};

  PLOAD(st0, 0);
  PWRITE(st0, 0);
  PLOAD(st1, 32);

#pragma unroll
  for (int ks = 0; ks < 12; ++ks) {
    SOFT_BARRIER();
    if (ks < 10) {
      if ((ks & 1) == 0) PLOAD(st0, (ks + 2) * 32);
      else               PLOAD(st1, (ks + 2) * 32);
    }
    int cur = ks & 1;
    short8 af[4], bfr[4];
#pragma unroll
    for (int mi = 0; mi < 4; ++mi)
      af[mi] = *(const short8*)&sA[cur][(wm * 64 + mi * 16 + l15) * 40 + l4 * 8];
#pragma unroll
    for (int ni = 0; ni < 4; ++ni)
      bfr[ni] = *(const short8*)&sB[cur][(wn * 64 + ni * 16 + l15) * 40 + l4 * 8];
#pragma unroll
    for (int mi = 0; mi < 4; ++mi)
#pragma unroll
      for (int ni = 0; ni < 4; ++ni)
        acc[mi][ni] = MFMA(af[mi], bfr[ni], acc[mi][ni], 0, 0, 0);
    if (ks < 11) {
      if ((ks & 1) == 0) PWRITE(st1, 1);
      else               PWRITE(st0, 0);
    }
  }
#undef PLOAD
#undef PWRITE

  for (int mi = 0; mi < 4; ++mi)
    for (int ni = 0; ni < 4; ++ni)
      for (int r = 0; r < 4; ++r) {
        int o = o0 + wm * 64 + mi * 16 + (l4 << 2) + r;
        int p = p0 + wn * 64 + ni * 16 + l15;
        if (p < NPF)
          out[((size_t)b * DIM + o) * NPF + p] = acc[mi][ni][r];
      }
}

extern "C" void kernel_launch(void* const* d_in, const int* in_sizes, int n_in,
                              void* d_out, int out_size, void* d_ws, size_t ws_size,
                              hipStream_t stream) {
  const float* x     = (const float*)d_in[0];
  const float* wqkv  = (const float*)d_in[1];
  const float* wproj = (const float*)d_in[2];
  const float* cpb   = (const float*)d_in[3];
  float* out = (float*)d_out;

  char* ws = (char*)d_ws;
  float* bias = (float*)ws;                       // 115248 B
  int*   rmap = (int*)(ws + 115712);              // -> 131072
  ushort* wqb = (ushort*)(ws + 131072);           // 884736 B
  ushort* wpb = (ushort*)(ws + 1015808);          // 294912 B -> 1310720
  const size_t QKV_B = (size_t)16 * 1152 * NPF * 2;   // 115.6 MB
  ushort* qkv = (ushort*)(ws + 1310720);
  ushort* xw  = (ushort*)(ws + 1310720 + QKV_B);      // 38.5 MB (ws >= 155.5 MB proven)

  hipLaunchKernelGGL(k_bias, dim3(113), dim3(256), 0, stream, cpb, bias);
  hipLaunchKernelGGL(k_rmap, dim3(13), dim3(256), 0, stream, rmap);
  hipLaunchKernelGGL(k_wcvt, dim3(288), dim3(256), 0, stream, wqkv, wproj, wqb, wpb);
  hipLaunchKernelGGL(k_xw, dim3(1176), dim3(256), 0, stream, x, rmap, xw);
  hipLaunchKernelGGL(k_qkv_pm, dim3(1872), dim3(256), 0, stream, xw, wqb, qkv);
  hipLaunchKernelGGL(k_attn_pm, dim3(NWIN * HEADS), dim3(64), 0, stream, qkv, bias);
  hipLaunchKernelGGL(k_proj_pm, dim3(1200), dim3(256), 0, stream, qkv, wpb, out);
}

// Round 23
// 258.516 us; speedup vs baseline: 1.9958x; 1.1080x over previous
//
#include <hip/hip_runtime.h>
#include <hip/hip_bf16.h>
#include <math.h>

#define DIM   384
#define HEADS 12
#define HD    32
#define WIN   7
#define NPIX  49
#define IMG   56
#define NPF   3136
#define NWIN  1024

typedef __attribute__((ext_vector_type(8))) short short8;
typedef __attribute__((ext_vector_type(4))) float f32x4;
typedef __attribute__((ext_vector_type(4))) float f4;
typedef __attribute__((ext_vector_type(4))) unsigned short us4;
typedef __attribute__((ext_vector_type(8))) unsigned short us8;
#define MFMA __builtin_amdgcn_mfma_f32_16x16x32_bf16

#define SOFT_BARRIER()                                         \
  do {                                                         \
    asm volatile("s_waitcnt lgkmcnt(0)" ::: "memory");         \
    __builtin_amdgcn_s_barrier();                              \
  } while (0)

__device__ inline ushort tob(float f) {
  unsigned u; __builtin_memcpy(&u, &f, 4);
  u += 0x7fffu + ((u >> 16) & 1u);
  return (ushort)(u >> 16);
}

// ---------------- bias table ----------------
__global__ void k_bias(const float* __restrict__ cpb, float* __restrict__ bias) {
  int idx = blockIdx.x * 256 + threadIdx.x;
  if (idx >= HEADS * NPIX * NPIX) return;
  int m = idx % NPIX;
  int n = (idx / NPIX) % NPIX;
  int h = idx / (NPIX * NPIX);
  int sy = (n / WIN - m / WIN) + (WIN - 1);
  int sx = (n % WIN - m % WIN) + (WIN - 1);
  const double inv_log_beta = 1.0 / log(1.3);
  double fy = (sy == 0 ? 0.0 : log1p((double)sy) * inv_log_beta) + 6.0;
  double fx = (sx == 0 ? 0.0 : log1p((double)sx) * inv_log_beta) + 6.0;
  fy = fmin(12.0, fmax(0.0, fy));
  fx = fmin(12.0, fmax(0.0, fx));
  int ridx = (int)(fy * 13.0 + fx);
  bias[idx] = cpb[ridx * HEADS + h];
}

__global__ void k_rmap(int* __restrict__ rmap) {
  int p = blockIdx.x * 256 + threadIdx.x;
  if (p < NPF) {
    int wb = p / NPIX, n = p - (p / NPIX) * NPIX;
    int gy = wb >> 3, gx = wb & 7;
    int wy = n / WIN, wx = n - (n / WIN) * WIN;
    rmap[p] = ((gy * WIN + wy + 4) % IMG) * IMG + (gx * WIN + wx + 4) % IMG;
  }
}

// ---------------- weights -> bf16 (once) ----------------
__global__ void k_wcvt(const float* __restrict__ wqkv, const float* __restrict__ wproj,
                       ushort* __restrict__ wqb, ushort* __restrict__ wpb) {
  int i = blockIdx.x * 256 + threadIdx.x;
  const int nq = 1152 * DIM / 8;
  const int np = DIM * DIM / 8;
  if (i < nq) {
    f4 a = *(const f4*)&wqkv[i * 8];
    f4 b = *(const f4*)&wqkv[i * 8 + 4];
    us8 u; u[0]=tob(a[0]);u[1]=tob(a[1]);u[2]=tob(a[2]);u[3]=tob(a[3]);
    u[4]=tob(b[0]);u[5]=tob(b[1]);u[6]=tob(b[2]);u[7]=tob(b[3]);
    *(us8*)&wqb[i * 8] = u;
  } else if (i < nq + np) {
    int j = i - nq;
    f4 a = *(const f4*)&wproj[j * 8];
    f4 b = *(const f4*)&wproj[j * 8 + 4];
    us8 u; u[0]=tob(a[0]);u[1]=tob(a[1]);u[2]=tob(a[2]);u[3]=tob(a[3]);
    u[4]=tob(b[0]);u[5]=tob(b[1]);u[6]=tob(b[2]);u[7]=tob(b[3]);
    *(us8*)&wpb[j * 8] = u;
  }
}

// ---------------- x -> xw[b][p'][c] bf16, 6-way channel-split ---------------
__global__ __launch_bounds__(256) void k_xw(const float* __restrict__ x,
                                            const int* __restrict__ rmap,
                                            ushort* __restrict__ xw) {
  int gid = blockIdx.x * 256 + threadIdx.x;   // 16*6*3136 exact
  int p  = gid % NPF;
  int cc = (gid / NPF) % 6;
  int b  = gid / (6 * NPF);
  int sp = rmap[p];
  const float* xs = x + (size_t)b * DIM * NPF + (size_t)(cc * 64) * NPF + sp;
  ushort* xd = xw + ((size_t)b * NPF + p) * DIM + cc * 64;
  for (int c0 = 0; c0 < 64; c0 += 8) {
    us8 u;
#pragma unroll
    for (int i = 0; i < 8; ++i) u[i] = tob(xs[(size_t)(c0 + i) * NPF]);
    *(us8*)&xd[c0] = u;
  }
}

// ---------------- QKV GEMM: coalesced 4-lanes-per-row staging ---------------
// Staging map: lane group of 4 covers chunks 0..3 (64 B, one cache line) of one
// row; wave touches 16 lines/instruction instead of 64.
__global__ __launch_bounds__(256) void k_qkv_pm(const ushort* __restrict__ xw,
                                                const ushort* __restrict__ wqb,
                                                ushort* __restrict__ qkv) {
  __shared__ __align__(16) ushort sA[2][128 * 40];
  __shared__ __align__(16) ushort sB[2][256 * 40];
  int t   = threadIdx.x;
  int bid = blockIdx.x;
  int swz = (bid & 7) * 234 + (bid >> 3);   // 1872 = 8*234, bijective
  int o0  = (swz % 9) * 128;
  int pbt = swz / 9;
  int p0  = (pbt % 13) * 256;
  int b   = pbt / 13;

  int lane = t & 63, w = t >> 6;
  int wm = w >> 1, wn = w & 1;
  int l15 = lane & 15, l4 = lane >> 4;

  // A: 2 units/thread; unit u -> row u>>2 (0..127), chunk (u&3)*8
  int ra0 = t >> 2,          ca0 = (t & 3) * 8;
  int ra1 = (t + 256) >> 2,  ca1 = ((t + 256) & 3) * 8;
  const ushort* apt0 = wqb + (size_t)(o0 + ra0) * DIM + ca0;
  const ushort* apt1 = wqb + (size_t)(o0 + ra1) * DIM + ca1;
  // B: 4 rows/thread; rows rb+64j, chunk cb
  int rb = t >> 2, cb = (t & 3) * 8;
  const ushort* bpt_[4];
#pragma unroll
  for (int j = 0; j < 4; ++j) {
    int pr = p0 + rb + 64 * j;
    if (pr >= NPF) pr = NPF - 1;
    bpt_[j] = xw + ((size_t)b * NPF + pr) * DIM + cb;
  }

  struct Stage { us8 a0, a1, b0, b1, b2, b3; };
  Stage st0, st1;

#define QLOAD(S, K0)                                    \
  do {                                                  \
    (S).a0 = *(const us8*)&apt0[(K0)];                  \
    (S).a1 = *(const us8*)&apt1[(K0)];                  \
    (S).b0 = *(const us8*)&bpt_[0][(K0)];               \
    (S).b1 = *(const us8*)&bpt_[1][(K0)];               \
    (S).b2 = *(const us8*)&bpt_[2][(K0)];               \
    (S).b3 = *(const us8*)&bpt_[3][(K0)];               \
  } while (0)
#define QWRITE(S, BUF)                                  \
  do {                                                  \
    *(us8*)&sA[(BUF)][ra0 * 40 + ca0] = (S).a0;         \
    *(us8*)&sA[(BUF)][ra1 * 40 + ca1] = (S).a1;         \
    *(us8*)&sB[(BUF)][(rb)       * 40 + cb] = (S).b0;   \
    *(us8*)&sB[(BUF)][(rb +  64) * 40 + cb] = (S).b1;   \
    *(us8*)&sB[(BUF)][(rb + 128) * 40 + cb] = (S).b2;   \
    *(us8*)&sB[(BUF)][(rb + 192) * 40 + cb] = (S).b3;   \
  } while (0)

  f32x4 acc[4][8] = {};

  QLOAD(st0, 0);
  QWRITE(st0, 0);
  QLOAD(st1, 32);

#pragma unroll
  for (int ks = 0; ks < 12; ++ks) {
    SOFT_BARRIER();
    if (ks < 10) {
      if ((ks & 1) == 0) QLOAD(st0, (ks + 2) * 32);
      else               QLOAD(st1, (ks + 2) * 32);
    }
    int cur = ks & 1;
    short8 af[4], bfr[8];
#pragma unroll
    for (int mi = 0; mi < 4; ++mi)
      af[mi] = *(const short8*)&sA[cur][(wm * 64 + mi * 16 + l15) * 40 + l4 * 8];
#pragma unroll
    for (int ni = 0; ni < 8; ++ni)
      bfr[ni] = *(const short8*)&sB[cur][(wn * 128 + ni * 16 + l15) * 40 + l4 * 8];
#pragma unroll
    for (int mi = 0; mi < 4; ++mi)
#pragma unroll
      for (int ni = 0; ni < 8; ++ni)
        acc[mi][ni] = MFMA(af[mi], bfr[ni], acc[mi][ni], 0, 0, 0);
    if (ks < 11) {
      if ((ks & 1) == 0) QWRITE(st1, 1);
      else               QWRITE(st0, 0);
    }
  }
#undef QLOAD
#undef QWRITE

#pragma unroll
  for (int mi = 0; mi < 4; ++mi)
#pragma unroll
    for (int ni = 0; ni < 8; ++ni) {
      int p = p0 + wn * 128 + ni * 16 + l15;
      if (p < NPF) {
        us4 u;
#pragma unroll
        for (int r = 0; r < 4; ++r) u[r] = tob(acc[mi][ni][r]);
        *(us4*)&qkv[((size_t)b * NPF + p) * 1152 + o0 + wm * 64 + mi * 16 + (l4 << 2)] = u;
      }
    }
}

// ---------------- attention (r12 verbatim) ----------------
__global__ __launch_bounds__(64) void k_attn_pm(ushort* __restrict__ qkv,
                                                const float* __restrict__ bias) {
  __shared__ __align__(16) ushort smem[8992];
  ushort* sq  = smem;          // [64][40]
  ushort* skt = smem + 2560;   // [64][40]
  ushort* svt = smem + 5120;   // [32][72]
  ushort* stg = smem + 7424;   // [49][32]
  ushort* pa  = smem;          // [64][72] overlays sq/skt

  int t = threadIdx.x;
  int bid = blockIdx.x;
  int swz = (bid & 7) * 1536 + (bid >> 3);   // 12288 = 8*1536
  int h = swz % HEADS, wb = swz / HEADS;
  int b = wb >> 6;
  int w49 = (wb & 63) * NPIX;
  ushort* qrow = qkv + ((size_t)b * NPF + w49) * 1152 + h * HD;

  for (int idx = t; idx < 32 * 23; idx += 64) {
    int d = idx / 23, mm = 49 + (idx - (idx / 23) * 23);
    svt[d * 72 + mm] = 0;
  }
  for (int idx = t; idx < NPIX * 4; idx += 64) {
    int n = idx >> 2, s = (idx & 3) * 8;
    *(us8*)&sq [n * 40 + s] = *(const us8*)&qrow[(size_t)n * 1152 + s];
    *(us8*)&skt[n * 40 + s] = *(const us8*)&qrow[(size_t)n * 1152 + DIM + s];
    *(us8*)&stg[n * 32 + s] = *(const us8*)&qrow[(size_t)n * 1152 + 2 * DIM + s];
  }
  __syncthreads();
  for (int idx = t; idx < HD * NPIX; idx += 64) {
    int d = idx / NPIX, m = idx - d * NPIX;
    svt[d * 72 + m] = stg[m * 32 + d];
  }
  __syncthreads();

  int l15 = t & 15, l4 = t >> 4;
  f32x4 acc[4][4] = {};
  {
    short8 af[4], bfr[4];
#pragma unroll
    for (int mi = 0; mi < 4; ++mi) af[mi]  = *(const short8*)&sq [(mi * 16 + l15) * 40 + l4 * 8];
#pragma unroll
    for (int ni = 0; ni < 4; ++ni) bfr[ni] = *(const short8*)&skt[(ni * 16 + l15) * 40 + l4 * 8];
#pragma unroll
    for (int mi = 0; mi < 4; ++mi)
#pragma unroll
      for (int ni = 0; ni < 4; ++ni)
        acc[mi][ni] = MFMA(af[mi], bfr[ni], acc[mi][ni], 0, 0, 0);
  }

  const float scale = 0.17677669529663687f;
  const float* bh = bias + h * NPIX * NPIX;
  float mx[16], sm[16];
#pragma unroll
  for (int mi = 0; mi < 4; ++mi)
#pragma unroll
    for (int r = 0; r < 4; ++r) {
      int n = mi * 16 + (l4 << 2) + r;
      float vmax = -3e38f;
#pragma unroll
      for (int ni = 0; ni < 4; ++ni) {
        int m = ni * 16 + l15;
        float s = (m < NPIX)
                    ? acc[mi][ni][r] * scale + ((n < NPIX) ? bh[n * NPIX + m] : 0.f)
                    : -3e38f;
        acc[mi][ni][r] = s;
        vmax = fmaxf(vmax, s);
      }
      mx[mi * 4 + r] = vmax;
    }
#pragma unroll
  for (int i = 1; i < 16; i <<= 1)
#pragma unroll
    for (int j = 0; j < 16; ++j) mx[j] = fmaxf(mx[j], __shfl_xor(mx[j], i));
#pragma unroll
  for (int mi = 0; mi < 4; ++mi)
#pragma unroll
    for (int r = 0; r < 4; ++r) {
      float s = 0.f;
#pragma unroll
      for (int ni = 0; ni < 4; ++ni) {
        float e = expf(acc[mi][ni][r] - mx[mi * 4 + r]);
        acc[mi][ni][r] = e;
        s += e;
      }
      sm[mi * 4 + r] = s;
    }
#pragma unroll
  for (int i = 1; i < 16; i <<= 1)
#pragma unroll
    for (int j = 0; j < 16; ++j) sm[j] += __shfl_xor(sm[j], i);

  __syncthreads();
#pragma unroll
  for (int mi = 0; mi < 4; ++mi)
#pragma unroll
    for (int r = 0; r < 4; ++r) {
      float ri = 1.f / sm[mi * 4 + r];
      int n = mi * 16 + (l4 << 2) + r;
#pragma unroll
      for (int ni = 0; ni < 4; ++ni)
        pa[n * 72 + ni * 16 + l15] = tob(acc[mi][ni][r] * ri);
    }
  __syncthreads();

  f32x4 yac[4][2] = {};
#pragma unroll
  for (int ks = 0; ks < 2; ++ks) {
    short8 pf[4], vf[2];
#pragma unroll
    for (int mi = 0; mi < 4; ++mi) pf[mi] = *(const short8*)&pa [(mi * 16 + l15) * 72 + ks * 32 + l4 * 8];
#pragma unroll
    for (int nd = 0; nd < 2; ++nd) vf[nd] = *(const short8*)&svt[(nd * 16 + l15) * 72 + ks * 32 + l4 * 8];
#pragma unroll
    for (int mi = 0; mi < 4; ++mi)
#pragma unroll
      for (int nd = 0; nd < 2; ++nd)
        yac[mi][nd] = MFMA(pf[mi], vf[nd], yac[mi][nd], 0, 0, 0);
  }
#pragma unroll
  for (int mi = 0; mi < 4; ++mi)
#pragma unroll
    for (int nd = 0; nd < 2; ++nd) {
      int nb = mi * 16 + (l4 << 2);
      int d = nd * 16 + l15;
#pragma unroll
      for (int r = 0; r < 4; ++r)
        if (nb + r < NPIX) qrow[(size_t)(nb + r) * 1152 + d] = tob(yac[mi][nd][r]);
    }
}

// ---------------- proj GEMM: coalesced 4-lanes-per-row staging --------------
__global__ __launch_bounds__(256) void k_proj_pm(const ushort* __restrict__ qkv,
                                                 const ushort* __restrict__ wpb,
                                                 float* __restrict__ out) {
  __shared__ __align__(16) ushort sA[2][128 * 40];
  __shared__ __align__(16) ushort sB[2][128 * 40];
  __shared__ int srm[128];
  int t   = threadIdx.x;
  int bid = blockIdx.x;
  int swz = (bid & 7) * 150 + (bid >> 3);   // 1200 = 8*150
  int o0  = (swz % 3) * 128;
  int pb  = swz / 3;
  int p0  = (pb % 25) * 128;
  int b   = pb / 25;
  if (t < 128) {
    int pg = p0 + t;
    if (pg >= NPF) pg = 0;
    int si = (pg / IMG + 53) % IMG, sj = (pg % IMG + 53) % IMG;
    srm[t] = ((si / WIN) * 8 + sj / WIN) * NPIX + (si % WIN) * WIN + (sj % WIN);
  }
  __syncthreads();

  int lane = t & 63, w = t >> 6;
  int wm = w >> 1, wn = w & 1;
  int l15 = lane & 15, l4 = lane >> 4;

  // A: units t, t+256 -> row u>>2 (0..127), chunk (u&3)*8
  int ra0 = t >> 2,          ca0 = (t & 3) * 8;
  int ra1 = (t + 256) >> 2,  ca1 = ((t + 256) & 3) * 8;
  const ushort* apt0 = wpb + (size_t)(o0 + ra0) * DIM + ca0;
  const ushort* apt1 = wpb + (size_t)(o0 + ra1) * DIM + ca1;
  // B: units t, t+256 -> row u>>2 via srm, chunk (u&3)*8
  const ushort* bpt0 = qkv + ((size_t)b * NPF + srm[ra0]) * 1152 + ca0;
  const ushort* bpt1 = qkv + ((size_t)b * NPF + srm[ra1]) * 1152 + ca1;

  struct Stage { us8 a0, a1, b0, b1; };
  Stage st0, st1;

#define PLOAD(S, K0)                                    \
  do {                                                  \
    (S).a0 = *(const us8*)&apt0[(K0)];                  \
    (S).a1 = *(const us8*)&apt1[(K0)];                  \
    (S).b0 = *(const us8*)&bpt0[(K0)];                  \
    (S).b1 = *(const us8*)&bpt1[(K0)];                  \
  } while (0)
#define PWRITE(S, BUF)                                  \
  do {                                                  \
    *(us8*)&sA[(BUF)][ra0 * 40 + ca0] = (S).a0;         \
    *(us8*)&sA[(BUF)][ra1 * 40 + ca1] = (S).a1;         \
    *(us8*)&sB[(BUF)][ra0 * 40 + ca0] = (S).b0;         \
    *(us8*)&sB[(BUF)][ra1 * 40 + ca1] = (S).b1;         \
  } while (0)

  f32x4 acc[4][4] = {};

  PLOAD(st0, 0);
  PWRITE(st0, 0);
  PLOAD(st1, 32);

#pragma unroll
  for (int ks = 0; ks < 12; ++ks) {
    SOFT_BARRIER();
    if (ks < 10) {
      if ((ks & 1) == 0) PLOAD(st0, (ks + 2) * 32);
      else               PLOAD(st1, (ks + 2) * 32);
    }
    int cur = ks & 1;
    short8 af[4], bfr[4];
#pragma unroll
    for (int mi = 0; mi < 4; ++mi)
      af[mi] = *(const short8*)&sA[cur][(wm * 64 + mi * 16 + l15) * 40 + l4 * 8];
#pragma unroll
    for (int ni = 0; ni < 4; ++ni)
      bfr[ni] = *(const short8*)&sB[cur][(wn * 64 + ni * 16 + l15) * 40 + l4 * 8];
#pragma unroll
    for (int mi = 0; mi < 4; ++mi)
#pragma unroll
      for (int ni = 0; ni < 4; ++ni)
        acc[mi][ni] = MFMA(af[mi], bfr[ni], acc[mi][ni], 0, 0, 0);
    if (ks < 11) {
      if ((ks & 1) == 0) PWRITE(st1, 1);
      else               PWRITE(st0, 0);
    }
  }
#undef PLOAD
#undef PWRITE

  for (int mi = 0; mi < 4; ++mi)
    for (int ni = 0; ni < 4; ++ni)
      for (int r = 0; r < 4; ++r) {
        int o = o0 + wm * 64 + mi * 16 + (l4 << 2) + r;
        int p = p0 + wn * 64 + ni * 16 + l15;
        if (p < NPF)
          out[((size_t)b * DIM + o) * NPF + p] = acc[mi][ni][r];
      }
}

extern "C" void kernel_launch(void* const* d_in, const int* in_sizes, int n_in,
                              void* d_out, int out_size, void* d_ws, size_t ws_size,
                              hipStream_t stream) {
  const float* x     = (const float*)d_in[0];
  const float* wqkv  = (const float*)d_in[1];
  const float* wproj = (const float*)d_in[2];
  const float* cpb   = (const float*)d_in[3];
  float* out = (float*)d_out;

  char* ws = (char*)d_ws;
  float* bias = (float*)ws;                       // 115248 B
  int*   rmap = (int*)(ws + 115712);              // -> 131072
  ushort* wqb = (ushort*)(ws + 131072);           // 884736 B
  ushort* wpb = (ushort*)(ws + 1015808);          // 294912 B -> 1310720
  const size_t QKV_B = (size_t)16 * 1152 * NPF * 2;   // 115.6 MB
  ushort* qkv = (ushort*)(ws + 1310720);
  ushort* xw  = (ushort*)(ws + 1310720 + QKV_B);      // 38.5 MB (ws >= 155.5 MB proven)

  hipLaunchKernelGGL(k_bias, dim3(113), dim3(256), 0, stream, cpb, bias);
  hipLaunchKernelGGL(k_rmap, dim3(13), dim3(256), 0, stream, rmap);
  hipLaunchKernelGGL(k_wcvt, dim3(288), dim3(256), 0, stream, wqkv, wproj, wqb, wpb);
  hipLaunchKernelGGL(k_xw, dim3(1176), dim3(256), 0, stream, x, rmap, xw);
  hipLaunchKernelGGL(k_qkv_pm, dim3(1872), dim3(256), 0, stream, xw, wqb, qkv);
  hipLaunchKernelGGL(k_attn_pm, dim3(NWIN * HEADS), dim3(64), 0, stream, qkv, bias);
  hipLaunchKernelGGL(k_proj_pm, dim3(1200), dim3(256), 0, stream, qkv, wpb, out);
}

// Round 24
// 246.396 us; speedup vs baseline: 2.0940x; 1.0492x over previous
//
#include <hip/hip_runtime.h>
#include <hip/hip_bf16.h>
#include <math.h>

#define DIM   384
#define HEADS 12
#define HD    32
#define WIN   7
#define NPIX  49
#define IMG   56
#define NPF   3136
#define NWIN  1024

typedef __attribute__((ext_vector_type(8))) short short8;
typedef __attribute__((ext_vector_type(4))) float f32x4;
typedef __attribute__((ext_vector_type(4))) float f4;
typedef __attribute__((ext_vector_type(4))) unsigned short us4;
typedef __attribute__((ext_vector_type(8))) unsigned short us8;
#define MFMA __builtin_amdgcn_mfma_f32_16x16x32_bf16

#define SOFT_BARRIER()                                         \
  do {                                                         \
    asm volatile("s_waitcnt lgkmcnt(0)" ::: "memory");         \
    __builtin_amdgcn_s_barrier();                              \
  } while (0)

__device__ inline ushort tob(float f) {
  unsigned u; __builtin_memcpy(&u, &f, 4);
  u += 0x7fffu + ((u >> 16) & 1u);
  return (ushort)(u >> 16);
}

// ---------------- bias table ----------------
__global__ void k_bias(const float* __restrict__ cpb, float* __restrict__ bias) {
  int idx = blockIdx.x * 256 + threadIdx.x;
  if (idx >= HEADS * NPIX * NPIX) return;
  int m = idx % NPIX;
  int n = (idx / NPIX) % NPIX;
  int h = idx / (NPIX * NPIX);
  int sy = (n / WIN - m / WIN) + (WIN - 1);
  int sx = (n % WIN - m % WIN) + (WIN - 1);
  const double inv_log_beta = 1.0 / log(1.3);
  double fy = (sy == 0 ? 0.0 : log1p((double)sy) * inv_log_beta) + 6.0;
  double fx = (sx == 0 ? 0.0 : log1p((double)sx) * inv_log_beta) + 6.0;
  fy = fmin(12.0, fmax(0.0, fy));
  fx = fmin(12.0, fmax(0.0, fx));
  int ridx = (int)(fy * 13.0 + fx);
  bias[idx] = cpb[ridx * HEADS + h];
}

__global__ void k_rmap(int* __restrict__ rmap) {
  int p = blockIdx.x * 256 + threadIdx.x;
  if (p < NPF) {
    int wb = p / NPIX, n = p - (p / NPIX) * NPIX;
    int gy = wb >> 3, gx = wb & 7;
    int wy = n / WIN, wx = n - (n / WIN) * WIN;
    rmap[p] = ((gy * WIN + wy + 4) % IMG) * IMG + (gx * WIN + wx + 4) % IMG;
  }
}

// ---------------- weights -> bf16 (once) ----------------
__global__ void k_wcvt(const float* __restrict__ wqkv, const float* __restrict__ wproj,
                       ushort* __restrict__ wqb, ushort* __restrict__ wpb) {
  int i = blockIdx.x * 256 + threadIdx.x;
  const int nq = 1152 * DIM / 8;
  const int np = DIM * DIM / 8;
  if (i < nq) {
    f4 a = *(const f4*)&wqkv[i * 8];
    f4 b = *(const f4*)&wqkv[i * 8 + 4];
    us8 u; u[0]=tob(a[0]);u[1]=tob(a[1]);u[2]=tob(a[2]);u[3]=tob(a[3]);
    u[4]=tob(b[0]);u[5]=tob(b[1]);u[6]=tob(b[2]);u[7]=tob(b[3]);
    *(us8*)&wqb[i * 8] = u;
  } else if (i < nq + np) {
    int j = i - nq;
    f4 a = *(const f4*)&wproj[j * 8];
    f4 b = *(const f4*)&wproj[j * 8 + 4];
    us8 u; u[0]=tob(a[0]);u[1]=tob(a[1]);u[2]=tob(a[2]);u[3]=tob(a[3]);
    u[4]=tob(b[0]);u[5]=tob(b[1]);u[6]=tob(b[2]);u[7]=tob(b[3]);
    *(us8*)&wpb[j * 8] = u;
  }
}

// ---------------- x -> xw[b][p'][c] bf16, 6-way channel-split ---------------
__global__ __launch_bounds__(256) void k_xw(const float* __restrict__ x,
                                            const int* __restrict__ rmap,
                                            ushort* __restrict__ xw) {
  int gid = blockIdx.x * 256 + threadIdx.x;   // 16*6*3136 exact
  int p  = gid % NPF;
  int cc = (gid / NPF) % 6;
  int b  = gid / (6 * NPF);
  int sp = rmap[p];
  const float* xs = x + (size_t)b * DIM * NPF + (size_t)(cc * 64) * NPF + sp;
  ushort* xd = xw + ((size_t)b * NPF + p) * DIM + cc * 64;
  for (int c0 = 0; c0 < 64; c0 += 8) {
    us8 u;
#pragma unroll
    for (int i = 0; i < 8; ++i) u[i] = tob(xs[(size_t)(c0 + i) * NPF]);
    *(us8*)&xd[c0] = u;
  }
}

// ---------------- QKV GEMM: coalesced 4-lanes-per-row staging (r23) ---------
__global__ __launch_bounds__(256) void k_qkv_pm(const ushort* __restrict__ xw,
                                                const ushort* __restrict__ wqb,
                                                ushort* __restrict__ qkv) {
  __shared__ __align__(16) ushort sA[2][128 * 40];
  __shared__ __align__(16) ushort sB[2][256 * 40];
  int t   = threadIdx.x;
  int bid = blockIdx.x;
  int swz = (bid & 7) * 234 + (bid >> 3);   // 1872 = 8*234, bijective
  int o0  = (swz % 9) * 128;
  int pbt = swz / 9;
  int p0  = (pbt % 13) * 256;
  int b   = pbt / 13;

  int lane = t & 63, w = t >> 6;
  int wm = w >> 1, wn = w & 1;
  int l15 = lane & 15, l4 = lane >> 4;

  int ra0 = t >> 2,          ca0 = (t & 3) * 8;
  int ra1 = (t + 256) >> 2,  ca1 = ((t + 256) & 3) * 8;
  const ushort* apt0 = wqb + (size_t)(o0 + ra0) * DIM + ca0;
  const ushort* apt1 = wqb + (size_t)(o0 + ra1) * DIM + ca1;
  int rb = t >> 2, cb = (t & 3) * 8;
  const ushort* bpt_[4];
#pragma unroll
  for (int j = 0; j < 4; ++j) {
    int pr = p0 + rb + 64 * j;
    if (pr >= NPF) pr = NPF - 1;
    bpt_[j] = xw + ((size_t)b * NPF + pr) * DIM + cb;
  }

  struct Stage { us8 a0, a1, b0, b1, b2, b3; };
  Stage st0, st1;

#define QLOAD(S, K0)                                    \
  do {                                                  \
    (S).a0 = *(const us8*)&apt0[(K0)];                  \
    (S).a1 = *(const us8*)&apt1[(K0)];                  \
    (S).b0 = *(const us8*)&bpt_[0][(K0)];               \
    (S).b1 = *(const us8*)&bpt_[1][(K0)];               \
    (S).b2 = *(const us8*)&bpt_[2][(K0)];               \
    (S).b3 = *(const us8*)&bpt_[3][(K0)];               \
  } while (0)
#define QWRITE(S, BUF)                                  \
  do {                                                  \
    *(us8*)&sA[(BUF)][ra0 * 40 + ca0] = (S).a0;         \
    *(us8*)&sA[(BUF)][ra1 * 40 + ca1] = (S).a1;         \
    *(us8*)&sB[(BUF)][(rb)       * 40 + cb] = (S).b0;   \
    *(us8*)&sB[(BUF)][(rb +  64) * 40 + cb] = (S).b1;   \
    *(us8*)&sB[(BUF)][(rb + 128) * 40 + cb] = (S).b2;   \
    *(us8*)&sB[(BUF)][(rb + 192) * 40 + cb] = (S).b3;   \
  } while (0)

  f32x4 acc[4][8] = {};

  QLOAD(st0, 0);
  QWRITE(st0, 0);
  QLOAD(st1, 32);

#pragma unroll
  for (int ks = 0; ks < 12; ++ks) {
    SOFT_BARRIER();
    if (ks < 10) {
      if ((ks & 1) == 0) QLOAD(st0, (ks + 2) * 32);
      else               QLOAD(st1, (ks + 2) * 32);
    }
    int cur = ks & 1;
    short8 af[4], bfr[8];
#pragma unroll
    for (int mi = 0; mi < 4; ++mi)
      af[mi] = *(const short8*)&sA[cur][(wm * 64 + mi * 16 + l15) * 40 + l4 * 8];
#pragma unroll
    for (int ni = 0; ni < 8; ++ni)
      bfr[ni] = *(const short8*)&sB[cur][(wn * 128 + ni * 16 + l15) * 40 + l4 * 8];
#pragma unroll
    for (int mi = 0; mi < 4; ++mi)
#pragma unroll
      for (int ni = 0; ni < 8; ++ni)
        acc[mi][ni] = MFMA(af[mi], bfr[ni], acc[mi][ni], 0, 0, 0);
    if (ks < 11) {
      if ((ks & 1) == 0) QWRITE(st1, 1);
      else               QWRITE(st0, 0);
    }
  }
#undef QLOAD
#undef QWRITE

#pragma unroll
  for (int mi = 0; mi < 4; ++mi)
#pragma unroll
    for (int ni = 0; ni < 8; ++ni) {
      int p = p0 + wn * 128 + ni * 16 + l15;
      if (p < NPF) {
        us4 u;
#pragma unroll
        for (int r = 0; r < 4; ++r) u[r] = tob(acc[mi][ni][r]);
        *(us4*)&qkv[((size_t)b * NPF + p) * 1152 + o0 + wm * 64 + mi * 16 + (l4 << 2)] = u;
      }
    }
}

// ---------------- attention: all frags direct from L2/L3; LDS = pa only -----
// 1 wave/block, LDS 9216 B -> ~17 blocks/CU. Q/K direct frags proven in r15.
// V gathered per-element; rows m>=49 multiply P=0 (reads land in xw, safe).
__global__ __launch_bounds__(64) void k_attn_pm(ushort* __restrict__ qkv,
                                                const float* __restrict__ bias) {
  __shared__ __align__(16) ushort pa[64 * 72];   // 9216 B

  int t = threadIdx.x;
  int bid = blockIdx.x;
  int swz = (bid & 7) * 1536 + (bid >> 3);   // 12288 = 8*1536
  int h = swz % HEADS, wb = swz / HEADS;
  int b = wb >> 6;
  int w49 = (wb & 63) * NPIX;
  ushort* qrow = qkv + ((size_t)b * NPF + w49) * 1152 + h * HD;

  int l15 = t & 15, l4 = t >> 4;

  // Q/K fragments straight from global (rows clamped; dup rows masked later)
  short8 af[4], bfr[4];
#pragma unroll
  for (int mi = 0; mi < 4; ++mi) {
    int rq = mi * 16 + l15; if (rq > 48) rq = 48;
    af[mi] = *(const short8*)&qrow[(size_t)rq * 1152 + l4 * 8];
  }
#pragma unroll
  for (int ni = 0; ni < 4; ++ni) {
    int rk = ni * 16 + l15; if (rk > 48) rk = 48;
    bfr[ni] = *(const short8*)&qrow[(size_t)rk * 1152 + DIM + l4 * 8];
  }
  f32x4 acc[4][4] = {};
#pragma unroll
  for (int mi = 0; mi < 4; ++mi)
#pragma unroll
    for (int ni = 0; ni < 4; ++ni)
      acc[mi][ni] = MFMA(af[mi], bfr[ni], acc[mi][ni], 0, 0, 0);

  // V fragments: direct gather V^T[d][m] = qrow[m*1152 + 768 + d]
  short8 vf[2][2];
#pragma unroll
  for (int ks = 0; ks < 2; ++ks)
#pragma unroll
    for (int nd = 0; nd < 2; ++nd) {
      us8 v;
#pragma unroll
      for (int e = 0; e < 8; ++e)
        v[e] = qrow[(size_t)(ks * 32 + l4 * 8 + e) * 1152 + 2 * DIM + nd * 16 + l15];
      vf[ks][nd] = (short8)v;
    }

  const float scale = 0.17677669529663687f;
  const float* bh = bias + h * NPIX * NPIX;
  float mx[16], sm[16];
#pragma unroll
  for (int mi = 0; mi < 4; ++mi)
#pragma unroll
    for (int r = 0; r < 4; ++r) {
      int n = mi * 16 + (l4 << 2) + r;
      float vmax = -3e38f;
#pragma unroll
      for (int ni = 0; ni < 4; ++ni) {
        int m = ni * 16 + l15;
        float s = (m < NPIX)
                    ? acc[mi][ni][r] * scale + ((n < NPIX) ? bh[n * NPIX + m] : 0.f)
                    : -3e38f;
        acc[mi][ni][r] = s;
        vmax = fmaxf(vmax, s);
      }
      mx[mi * 4 + r] = vmax;
    }
#pragma unroll
  for (int i = 1; i < 16; i <<= 1)
#pragma unroll
    for (int j = 0; j < 16; ++j) mx[j] = fmaxf(mx[j], __shfl_xor(mx[j], i));
#pragma unroll
  for (int mi = 0; mi < 4; ++mi)
#pragma unroll
    for (int r = 0; r < 4; ++r) {
      float s = 0.f;
#pragma unroll
      for (int ni = 0; ni < 4; ++ni) {
        float e = expf(acc[mi][ni][r] - mx[mi * 4 + r]);
        acc[mi][ni][r] = e;
        s += e;
      }
      sm[mi * 4 + r] = s;
    }
#pragma unroll
  for (int i = 1; i < 16; i <<= 1)
#pragma unroll
    for (int j = 0; j < 16; ++j) sm[j] += __shfl_xor(sm[j], i);

  // P -> LDS (single wave: intra-wave DS ordering, no barrier needed)
#pragma unroll
  for (int mi = 0; mi < 4; ++mi)
#pragma unroll
    for (int r = 0; r < 4; ++r) {
      float ri = 1.f / sm[mi * 4 + r];
      int n = mi * 16 + (l4 << 2) + r;
#pragma unroll
      for (int ni = 0; ni < 4; ++ni)
        pa[n * 72 + ni * 16 + l15] = tob(acc[mi][ni][r] * ri);
    }

  f32x4 yac[4][2] = {};
#pragma unroll
  for (int ks = 0; ks < 2; ++ks) {
    short8 pf[4];
#pragma unroll
    for (int mi = 0; mi < 4; ++mi) pf[mi] = *(const short8*)&pa[(mi * 16 + l15) * 72 + ks * 32 + l4 * 8];
#pragma unroll
    for (int mi = 0; mi < 4; ++mi)
#pragma unroll
      for (int nd = 0; nd < 2; ++nd)
        yac[mi][nd] = MFMA(pf[mi], vf[ks][nd], yac[mi][nd], 0, 0, 0);
  }
  // Y over own Q slice — disjoint across blocks
#pragma unroll
  for (int mi = 0; mi < 4; ++mi)
#pragma unroll
    for (int nd = 0; nd < 2; ++nd) {
      int nb = mi * 16 + (l4 << 2);
      int d = nd * 16 + l15;
#pragma unroll
      for (int r = 0; r < 4; ++r)
        if (nb + r < NPIX) qrow[(size_t)(nb + r) * 1152 + d] = tob(yac[mi][nd][r]);
    }
}

// ---------------- proj GEMM: coalesced 4-lanes-per-row staging (r23) --------
__global__ __launch_bounds__(256) void k_proj_pm(const ushort* __restrict__ qkv,
                                                 const ushort* __restrict__ wpb,
                                                 float* __restrict__ out) {
  __shared__ __align__(16) ushort sA[2][128 * 40];
  __shared__ __align__(16) ushort sB[2][128 * 40];
  __shared__ int srm[128];
  int t   = threadIdx.x;
  int bid = blockIdx.x;
  int swz = (bid & 7) * 150 + (bid >> 3);   // 1200 = 8*150
  int o0  = (swz % 3) * 128;
  int pb  = swz / 3;
  int p0  = (pb % 25) * 128;
  int b   = pb / 25;
  if (t < 128) {
    int pg = p0 + t;
    if (pg >= NPF) pg = 0;
    int si = (pg / IMG + 53) % IMG, sj = (pg % IMG + 53) % IMG;
    srm[t] = ((si / WIN) * 8 + sj / WIN) * NPIX + (si % WIN) * WIN + (sj % WIN);
  }
  __syncthreads();

  int lane = t & 63, w = t >> 6;
  int wm = w >> 1, wn = w & 1;
  int l15 = lane & 15, l4 = lane >> 4;

  int ra0 = t >> 2,          ca0 = (t & 3) * 8;
  int ra1 = (t + 256) >> 2,  ca1 = ((t + 256) & 3) * 8;
  const ushort* apt0 = wpb + (size_t)(o0 + ra0) * DIM + ca0;
  const ushort* apt1 = wpb + (size_t)(o0 + ra1) * DIM + ca1;
  const ushort* bpt0 = qkv + ((size_t)b * NPF + srm[ra0]) * 1152 + ca0;
  const ushort* bpt1 = qkv + ((size_t)b * NPF + srm[ra1]) * 1152 + ca1;

  struct Stage { us8 a0, a1, b0, b1; };
  Stage st0, st1;

#define PLOAD(S, K0)                                    \
  do {                                                  \
    (S).a0 = *(const us8*)&apt0[(K0)];                  \
    (S).a1 = *(const us8*)&apt1[(K0)];                  \
    (S).b0 = *(const us8*)&bpt0[(K0)];                  \
    (S).b1 = *(const us8*)&bpt1[(K0)];                  \
  } while (0)
#define PWRITE(S, BUF)                                  \
  do {                                                  \
    *(us8*)&sA[(BUF)][ra0 * 40 + ca0] = (S).a0;         \
    *(us8*)&sA[(BUF)][ra1 * 40 + ca1] = (S).a1;         \
    *(us8*)&sB[(BUF)][ra0 * 40 + ca0] = (S).b0;         \
    *(us8*)&sB[(BUF)][ra1 * 40 + ca1] = (S).b1;         \
  } while (0)

  f32x4 acc[4][4] = {};

  PLOAD(st0, 0);
  PWRITE(st0, 0);
  PLOAD(st1, 32);

#pragma unroll
  for (int ks = 0; ks < 12; ++ks) {
    SOFT_BARRIER();
    if (ks < 10) {
      if ((ks & 1) == 0) PLOAD(st0, (ks + 2) * 32);
      else               PLOAD(st1, (ks + 2) * 32);
    }
    int cur = ks & 1;
    short8 af[4], bfr[4];
#pragma unroll
    for (int mi = 0; mi < 4; ++mi)
      af[mi] = *(const short8*)&sA[cur][(wm * 64 + mi * 16 + l15) * 40 + l4 * 8];
#pragma unroll
    for (int ni = 0; ni < 4; ++ni)
      bfr[ni] = *(const short8*)&sB[cur][(wn * 64 + ni * 16 + l15) * 40 + l4 * 8];
#pragma unroll
    for (int mi = 0; mi < 4; ++mi)
#pragma unroll
      for (int ni = 0; ni < 4; ++ni)
        acc[mi][ni] = MFMA(af[mi], bfr[ni], acc[mi][ni], 0, 0, 0);
    if (ks < 11) {
      if ((ks & 1) == 0) PWRITE(st1, 1);
      else               PWRITE(st0, 0);
    }
  }
#undef PLOAD
#undef PWRITE

  for (int mi = 0; mi < 4; ++mi)
    for (int ni = 0; ni < 4; ++ni)
      for (int r = 0; r < 4; ++r) {
        int o = o0 + wm * 64 + mi * 16 + (l4 << 2) + r;
        int p = p0 + wn * 64 + ni * 16 + l15;
        if (p < NPF)
          out[((size_t)b * DIM + o) * NPF + p] = acc[mi][ni][r];
      }
}

extern "C" void kernel_launch(void* const* d_in, const int* in_sizes, int n_in,
                              void* d_out, int out_size, void* d_ws, size_t ws_size,
                              hipStream_t stream) {
  const float* x     = (const float*)d_in[0];
  const float* wqkv  = (const float*)d_in[1];
  const float* wproj = (const float*)d_in[2];
  const float* cpb   = (const float*)d_in[3];
  float* out = (float*)d_out;

  char* ws = (char*)d_ws;
  float* bias = (float*)ws;                       // 115248 B
  int*   rmap = (int*)(ws + 115712);              // -> 131072
  ushort* wqb = (ushort*)(ws + 131072);           // 884736 B
  ushort* wpb = (ushort*)(ws + 1015808);          // 294912 B -> 1310720
  const size_t QKV_B = (size_t)16 * 1152 * NPF * 2;   // 115.6 MB
  ushort* qkv = (ushort*)(ws + 1310720);
  ushort* xw  = (ushort*)(ws + 1310720 + QKV_B);      // 38.5 MB (ws >= 155.5 MB proven)

  hipLaunchKernelGGL(k_bias, dim3(113), dim3(256), 0, stream, cpb, bias);
  hipLaunchKernelGGL(k_rmap, dim3(13), dim3(256), 0, stream, rmap);
  hipLaunchKernelGGL(k_wcvt, dim3(288), dim3(256), 0, stream, wqkv, wproj, wqb, wpb);
  hipLaunchKernelGGL(k_xw, dim3(1176), dim3(256), 0, stream, x, rmap, xw);
  hipLaunchKernelGGL(k_qkv_pm, dim3(1872), dim3(256), 0, stream, xw, wqb, qkv);
  hipLaunchKernelGGL(k_attn_pm, dim3(NWIN * HEADS), dim3(64), 0, stream, qkv, bias);
  hipLaunchKernelGGL(k_proj_pm, dim3(1200), dim3(256), 0, stream, qkv, wpb, out);
}

// Round 25
// 235.812 us; speedup vs baseline: 2.1880x; 1.0449x over previous
//
#include <hip/hip_runtime.h>
#include <hip/hip_bf16.h>
#include <math.h>

#define DIM   384
#define HEADS 12
#define HD    32
#define WIN   7
#define NPIX  49
#define IMG   56
#define NPF   3136
#define NWIN  1024

typedef __attribute__((ext_vector_type(8))) short short8;
typedef __attribute__((ext_vector_type(4))) float f32x4;
typedef __attribute__((ext_vector_type(4))) float f4;
typedef __attribute__((ext_vector_type(4))) unsigned short us4;
typedef __attribute__((ext_vector_type(8))) unsigned short us8;
#define MFMA __builtin_amdgcn_mfma_f32_16x16x32_bf16

#define SOFT_BARRIER()                                         \
  do {                                                         \
    asm volatile("s_waitcnt lgkmcnt(0)" ::: "memory");         \
    __builtin_amdgcn_s_barrier();                              \
  } while (0)

__device__ inline ushort tob(float f) {
  unsigned u; __builtin_memcpy(&u, &f, 4);
  u += 0x7fffu + ((u >> 16) & 1u);
  return (ushort)(u >> 16);
}

// ---------------- bias table ----------------
__global__ void k_bias(const float* __restrict__ cpb, float* __restrict__ bias) {
  int idx = blockIdx.x * 256 + threadIdx.x;
  if (idx >= HEADS * NPIX * NPIX) return;
  int m = idx % NPIX;
  int n = (idx / NPIX) % NPIX;
  int h = idx / (NPIX * NPIX);
  int sy = (n / WIN - m / WIN) + (WIN - 1);
  int sx = (n % WIN - m % WIN) + (WIN - 1);
  const double inv_log_beta = 1.0 / log(1.3);
  double fy = (sy == 0 ? 0.0 : log1p((double)sy) * inv_log_beta) + 6.0;
  double fx = (sx == 0 ? 0.0 : log1p((double)sx) * inv_log_beta) + 6.0;
  fy = fmin(12.0, fmax(0.0, fy));
  fx = fmin(12.0, fmax(0.0, fx));
  int ridx = (int)(fy * 13.0 + fx);
  bias[idx] = cpb[ridx * HEADS + h];
}

__global__ void k_rmap(int* __restrict__ rmap) {
  int p = blockIdx.x * 256 + threadIdx.x;
  if (p < NPF) {
    int wb = p / NPIX, n = p - (p / NPIX) * NPIX;
    int gy = wb >> 3, gx = wb & 7;
    int wy = n / WIN, wx = n - (n / WIN) * WIN;
    rmap[p] = ((gy * WIN + wy + 4) % IMG) * IMG + (gx * WIN + wx + 4) % IMG;
  }
}

// ---------------- weights -> bf16 (once) ----------------
__global__ void k_wcvt(const float* __restrict__ wqkv, const float* __restrict__ wproj,
                       ushort* __restrict__ wqb, ushort* __restrict__ wpb) {
  int i = blockIdx.x * 256 + threadIdx.x;
  const int nq = 1152 * DIM / 8;
  const int np = DIM * DIM / 8;
  if (i < nq) {
    f4 a = *(const f4*)&wqkv[i * 8];
    f4 b = *(const f4*)&wqkv[i * 8 + 4];
    us8 u; u[0]=tob(a[0]);u[1]=tob(a[1]);u[2]=tob(a[2]);u[3]=tob(a[3]);
    u[4]=tob(b[0]);u[5]=tob(b[1]);u[6]=tob(b[2]);u[7]=tob(b[3]);
    *(us8*)&wqb[i * 8] = u;
  } else if (i < nq + np) {
    int j = i - nq;
    f4 a = *(const f4*)&wproj[j * 8];
    f4 b = *(const f4*)&wproj[j * 8 + 4];
    us8 u; u[0]=tob(a[0]);u[1]=tob(a[1]);u[2]=tob(a[2]);u[3]=tob(a[3]);
    u[4]=tob(b[0]);u[5]=tob(b[1]);u[6]=tob(b[2]);u[7]=tob(b[3]);
    *(us8*)&wpb[j * 8] = u;
  }
}

// ---------------- x -> xw[b][p'][c] bf16, 6-way channel-split ---------------
__global__ __launch_bounds__(256) void k_xw(const float* __restrict__ x,
                                            const int* __restrict__ rmap,
                                            ushort* __restrict__ xw) {
  int gid = blockIdx.x * 256 + threadIdx.x;   // 16*6*3136 exact
  int p  = gid % NPF;
  int cc = (gid / NPF) % 6;
  int b  = gid / (6 * NPF);
  int sp = rmap[p];
  const float* xs = x + (size_t)b * DIM * NPF + (size_t)(cc * 64) * NPF + sp;
  ushort* xd = xw + ((size_t)b * NPF + p) * DIM + cc * 64;
  for (int c0 = 0; c0 < 64; c0 += 8) {
    us8 u;
#pragma unroll
    for (int i = 0; i < 8; ++i) u[i] = tob(xs[(size_t)(c0 + i) * NPF]);
    *(us8*)&xd[c0] = u;
  }
}

// ---------------- QKV GEMM: 128x128 tile, 4 blocks/CU, coalesced staging ----
__global__ __launch_bounds__(256) void k_qkv_pm(const ushort* __restrict__ xw,
                                                const ushort* __restrict__ wqb,
                                                ushort* __restrict__ qkv) {
  __shared__ __align__(16) ushort sA[2][128 * 40];
  __shared__ __align__(16) ushort sB[2][128 * 40];
  int t   = threadIdx.x;
  int bid = blockIdx.x;
  int swz = (bid & 7) * 450 + (bid >> 3);   // 3600 = 8*450, bijective
  int o0  = (swz % 9) * 128;
  int pbt = swz / 9;
  int p0  = (pbt % 25) * 128;
  int b   = pbt / 25;

  int lane = t & 63, w = t >> 6;
  int wm = w >> 1, wn = w & 1;
  int l15 = lane & 15, l4 = lane >> 4;

  // A and B: 2 units/thread; unit u -> row u>>2 (0..127), chunk (u&3)*8
  int ra0 = t >> 2,          ca0 = (t & 3) * 8;
  int ra1 = (t + 256) >> 2,  ca1 = ((t + 256) & 3) * 8;
  const ushort* apt0 = wqb + (size_t)(o0 + ra0) * DIM + ca0;
  const ushort* apt1 = wqb + (size_t)(o0 + ra1) * DIM + ca1;
  int pr0 = p0 + ra0; if (pr0 >= NPF) pr0 = NPF - 1;
  int pr1 = p0 + ra1; if (pr1 >= NPF) pr1 = NPF - 1;
  const ushort* bpt0 = xw + ((size_t)b * NPF + pr0) * DIM + ca0;
  const ushort* bpt1 = xw + ((size_t)b * NPF + pr1) * DIM + ca1;

  struct Stage { us8 a0, a1, b0, b1; };
  Stage st0, st1;

#define QLOAD(S, K0)                                    \
  do {                                                  \
    (S).a0 = *(const us8*)&apt0[(K0)];                  \
    (S).a1 = *(const us8*)&apt1[(K0)];                  \
    (S).b0 = *(const us8*)&bpt0[(K0)];                  \
    (S).b1 = *(const us8*)&bpt1[(K0)];                  \
  } while (0)
#define QWRITE(S, BUF)                                  \
  do {                                                  \
    *(us8*)&sA[(BUF)][ra0 * 40 + ca0] = (S).a0;         \
    *(us8*)&sA[(BUF)][ra1 * 40 + ca1] = (S).a1;         \
    *(us8*)&sB[(BUF)][ra0 * 40 + ca0] = (S).b0;         \
    *(us8*)&sB[(BUF)][ra1 * 40 + ca1] = (S).b1;         \
  } while (0)

  f32x4 acc[4][4] = {};

  QLOAD(st0, 0);
  QWRITE(st0, 0);
  QLOAD(st1, 32);

#pragma unroll
  for (int ks = 0; ks < 12; ++ks) {
    SOFT_BARRIER();
    if (ks < 10) {
      if ((ks & 1) == 0) QLOAD(st0, (ks + 2) * 32);
      else               QLOAD(st1, (ks + 2) * 32);
    }
    int cur = ks & 1;
    short8 af[4], bfr[4];
#pragma unroll
    for (int mi = 0; mi < 4; ++mi)
      af[mi] = *(const short8*)&sA[cur][(wm * 64 + mi * 16 + l15) * 40 + l4 * 8];
#pragma unroll
    for (int ni = 0; ni < 4; ++ni)
      bfr[ni] = *(const short8*)&sB[cur][(wn * 64 + ni * 16 + l15) * 40 + l4 * 8];
#pragma unroll
    for (int mi = 0; mi < 4; ++mi)
#pragma unroll
      for (int ni = 0; ni < 4; ++ni)
        acc[mi][ni] = MFMA(af[mi], bfr[ni], acc[mi][ni], 0, 0, 0);
    if (ks < 11) {
      if ((ks & 1) == 0) QWRITE(st1, 1);
      else               QWRITE(st0, 0);
    }
  }
#undef QLOAD
#undef QWRITE

#pragma unroll
  for (int mi = 0; mi < 4; ++mi)
#pragma unroll
    for (int ni = 0; ni < 4; ++ni) {
      int p = p0 + wn * 64 + ni * 16 + l15;
      if (p < NPF) {
        us4 u;
#pragma unroll
        for (int r = 0; r < 4; ++r) u[r] = tob(acc[mi][ni][r]);
        *(us4*)&qkv[((size_t)b * NPF + p) * 1152 + o0 + wm * 64 + mi * 16 + (l4 << 2)] = u;
      }
    }
}

// ---------------- attention: direct frags, LDS = pa only (r24) --------------
__global__ __launch_bounds__(64) void k_attn_pm(ushort* __restrict__ qkv,
                                                const float* __restrict__ bias) {
  __shared__ __align__(16) ushort pa[64 * 72];   // 9216 B

  int t = threadIdx.x;
  int bid = blockIdx.x;
  int swz = (bid & 7) * 1536 + (bid >> 3);   // 12288 = 8*1536
  int h = swz % HEADS, wb = swz / HEADS;
  int b = wb >> 6;
  int w49 = (wb & 63) * NPIX;
  ushort* qrow = qkv + ((size_t)b * NPF + w49) * 1152 + h * HD;

  int l15 = t & 15, l4 = t >> 4;

  short8 af[4], bfr[4];
#pragma unroll
  for (int mi = 0; mi < 4; ++mi) {
    int rq = mi * 16 + l15; if (rq > 48) rq = 48;
    af[mi] = *(const short8*)&qrow[(size_t)rq * 1152 + l4 * 8];
  }
#pragma unroll
  for (int ni = 0; ni < 4; ++ni) {
    int rk = ni * 16 + l15; if (rk > 48) rk = 48;
    bfr[ni] = *(const short8*)&qrow[(size_t)rk * 1152 + DIM + l4 * 8];
  }
  f32x4 acc[4][4] = {};
#pragma unroll
  for (int mi = 0; mi < 4; ++mi)
#pragma unroll
    for (int ni = 0; ni < 4; ++ni)
      acc[mi][ni] = MFMA(af[mi], bfr[ni], acc[mi][ni], 0, 0, 0);

  short8 vf[2][2];
#pragma unroll
  for (int ks = 0; ks < 2; ++ks)
#pragma unroll
    for (int nd = 0; nd < 2; ++nd) {
      us8 v;
#pragma unroll
      for (int e = 0; e < 8; ++e)
        v[e] = qrow[(size_t)(ks * 32 + l4 * 8 + e) * 1152 + 2 * DIM + nd * 16 + l15];
      vf[ks][nd] = (short8)v;
    }

  const float scale = 0.17677669529663687f;
  const float* bh = bias + h * NPIX * NPIX;
  float mx[16], sm[16];
#pragma unroll
  for (int mi = 0; mi < 4; ++mi)
#pragma unroll
    for (int r = 0; r < 4; ++r) {
      int n = mi * 16 + (l4 << 2) + r;
      float vmax = -3e38f;
#pragma unroll
      for (int ni = 0; ni < 4; ++ni) {
        int m = ni * 16 + l15;
        float s = (m < NPIX)
                    ? acc[mi][ni][r] * scale + ((n < NPIX) ? bh[n * NPIX + m] : 0.f)
                    : -3e38f;
        acc[mi][ni][r] = s;
        vmax = fmaxf(vmax, s);
      }
      mx[mi * 4 + r] = vmax;
    }
#pragma unroll
  for (int i = 1; i < 16; i <<= 1)
#pragma unroll
    for (int j = 0; j < 16; ++j) mx[j] = fmaxf(mx[j], __shfl_xor(mx[j], i));
#pragma unroll
  for (int mi = 0; mi < 4; ++mi)
#pragma unroll
    for (int r = 0; r < 4; ++r) {
      float s = 0.f;
#pragma unroll
      for (int ni = 0; ni < 4; ++ni) {
        float e = expf(acc[mi][ni][r] - mx[mi * 4 + r]);
        acc[mi][ni][r] = e;
        s += e;
      }
      sm[mi * 4 + r] = s;
    }
#pragma unroll
  for (int i = 1; i < 16; i <<= 1)
#pragma unroll
    for (int j = 0; j < 16; ++j) sm[j] += __shfl_xor(sm[j], i);

#pragma unroll
  for (int mi = 0; mi < 4; ++mi)
#pragma unroll
    for (int r = 0; r < 4; ++r) {
      float ri = 1.f / sm[mi * 4 + r];
      int n = mi * 16 + (l4 << 2) + r;
#pragma unroll
      for (int ni = 0; ni < 4; ++ni)
        pa[n * 72 + ni * 16 + l15] = tob(acc[mi][ni][r] * ri);
    }

  f32x4 yac[4][2] = {};
#pragma unroll
  for (int ks = 0; ks < 2; ++ks) {
    short8 pf[4];
#pragma unroll
    for (int mi = 0; mi < 4; ++mi) pf[mi] = *(const short8*)&pa[(mi * 16 + l15) * 72 + ks * 32 + l4 * 8];
#pragma unroll
    for (int mi = 0; mi < 4; ++mi)
#pragma unroll
      for (int nd = 0; nd < 2; ++nd)
        yac[mi][nd] = MFMA(pf[mi], vf[ks][nd], yac[mi][nd], 0, 0, 0);
  }
#pragma unroll
  for (int mi = 0; mi < 4; ++mi)
#pragma unroll
    for (int nd = 0; nd < 2; ++nd) {
      int nb = mi * 16 + (l4 << 2);
      int d = nd * 16 + l15;
#pragma unroll
      for (int r = 0; r < 4; ++r)
        if (nb + r < NPIX) qrow[(size_t)(nb + r) * 1152 + d] = tob(yac[mi][nd][r]);
    }
}

// ---------------- proj GEMM: coalesced 4-lanes-per-row staging (r23) --------
__global__ __launch_bounds__(256) void k_proj_pm(const ushort* __restrict__ qkv,
                                                 const ushort* __restrict__ wpb,
                                                 float* __restrict__ out) {
  __shared__ __align__(16) ushort sA[2][128 * 40];
  __shared__ __align__(16) ushort sB[2][128 * 40];
  __shared__ int srm[128];
  int t   = threadIdx.x;
  int bid = blockIdx.x;
  int swz = (bid & 7) * 150 + (bid >> 3);   // 1200 = 8*150
  int o0  = (swz % 3) * 128;
  int pb  = swz / 3;
  int p0  = (pb % 25) * 128;
  int b   = pb / 25;
  if (t < 128) {
    int pg = p0 + t;
    if (pg >= NPF) pg = 0;
    int si = (pg / IMG + 53) % IMG, sj = (pg % IMG + 53) % IMG;
    srm[t] = ((si / WIN) * 8 + sj / WIN) * NPIX + (si % WIN) * WIN + (sj % WIN);
  }
  __syncthreads();

  int lane = t & 63, w = t >> 6;
  int wm = w >> 1, wn = w & 1;
  int l15 = lane & 15, l4 = lane >> 4;

  int ra0 = t >> 2,          ca0 = (t & 3) * 8;
  int ra1 = (t + 256) >> 2,  ca1 = ((t + 256) & 3) * 8;
  const ushort* apt0 = wpb + (size_t)(o0 + ra0) * DIM + ca0;
  const ushort* apt1 = wpb + (size_t)(o0 + ra1) * DIM + ca1;
  const ushort* bpt0 = qkv + ((size_t)b * NPF + srm[ra0]) * 1152 + ca0;
  const ushort* bpt1 = qkv + ((size_t)b * NPF + srm[ra1]) * 1152 + ca1;

  struct Stage { us8 a0, a1, b0, b1; };
  Stage st0, st1;

#define PLOAD(S, K0)                                    \
  do {                                                  \
    (S).a0 = *(const us8*)&apt0[(K0)];                  \
    (S).a1 = *(const us8*)&apt1[(K0)];                  \
    (S).b0 = *(const us8*)&bpt0[(K0)];                  \
    (S).b1 = *(const us8*)&bpt1[(K0)];                  \
  } while (0)
#define PWRITE(S, BUF)                                  \
  do {                                                  \
    *(us8*)&sA[(BUF)][ra0 * 40 + ca0] = (S).a0;         \
    *(us8*)&sA[(BUF)][ra1 * 40 + ca1] = (S).a1;         \
    *(us8*)&sB[(BUF)][ra0 * 40 + ca0] = (S).b0;         \
    *(us8*)&sB[(BUF)][ra1 * 40 + ca1] = (S).b1;         \
  } while (0)

  f32x4 acc[4][4] = {};

  PLOAD(st0, 0);
  PWRITE(st0, 0);
  PLOAD(st1, 32);

#pragma unroll
  for (int ks = 0; ks < 12; ++ks) {
    SOFT_BARRIER();
    if (ks < 10) {
      if ((ks & 1) == 0) PLOAD(st0, (ks + 2) * 32);
      else               PLOAD(st1, (ks + 2) * 32);
    }
    int cur = ks & 1;
    short8 af[4], bfr[4];
#pragma unroll
    for (int mi = 0; mi < 4; ++mi)
      af[mi] = *(const short8*)&sA[cur][(wm * 64 + mi * 16 + l15) * 40 + l4 * 8];
#pragma unroll
    for (int ni = 0; ni < 4; ++ni)
      bfr[ni] = *(const short8*)&sB[cur][(wn * 64 + ni * 16 + l15) * 40 + l4 * 8];
#pragma unroll
    for (int mi = 0; mi < 4; ++mi)
#pragma unroll
      for (int ni = 0; ni < 4; ++ni)
        acc[mi][ni] = MFMA(af[mi], bfr[ni], acc[mi][ni], 0, 0, 0);
    if (ks < 11) {
      if ((ks & 1) == 0) PWRITE(st1, 1);
      else               PWRITE(st0, 0);
    }
  }
#undef PLOAD
#undef PWRITE

  for (int mi = 0; mi < 4; ++mi)
    for (int ni = 0; ni < 4; ++ni)
      for (int r = 0; r < 4; ++r) {
        int o = o0 + wm * 64 + mi * 16 + (l4 << 2) + r;
        int p = p0 + wn * 64 + ni * 16 + l15;
        if (p < NPF)
          out[((size_t)b * DIM + o) * NPF + p] = acc[mi][ni][r];
      }
}

extern "C" void kernel_launch(void* const* d_in, const int* in_sizes, int n_in,
                              void* d_out, int out_size, void* d_ws, size_t ws_size,
                              hipStream_t stream) {
  const float* x     = (const float*)d_in[0];
  const float* wqkv  = (const float*)d_in[1];
  const float* wproj = (const float*)d_in[2];
  const float* cpb   = (const float*)d_in[3];
  float* out = (float*)d_out;

  char* ws = (char*)d_ws;
  float* bias = (float*)ws;                       // 115248 B
  int*   rmap = (int*)(ws + 115712);              // -> 131072
  ushort* wqb = (ushort*)(ws + 131072);           // 884736 B
  ushort* wpb = (ushort*)(ws + 1015808);          // 294912 B -> 1310720
  const size_t QKV_B = (size_t)16 * 1152 * NPF * 2;   // 115.6 MB
  ushort* qkv = (ushort*)(ws + 1310720);
  ushort* xw  = (ushort*)(ws + 1310720 + QKV_B);      // 38.5 MB (ws >= 155.5 MB proven)

  hipLaunchKernelGGL(k_bias, dim3(113), dim3(256), 0, stream, cpb, bias);
  hipLaunchKernelGGL(k_rmap, dim3(13), dim3(256), 0, stream, rmap);
  hipLaunchKernelGGL(k_wcvt, dim3(288), dim3(256), 0, stream, wqkv, wproj, wqb, wpb);
  hipLaunchKernelGGL(k_xw, dim3(1176), dim3(256), 0, stream, x, rmap, xw);
  hipLaunchKernelGGL(k_qkv_pm, dim3(3600), dim3(256), 0, stream, xw, wqb, qkv);
  hipLaunchKernelGGL(k_attn_pm, dim3(NWIN * HEADS), dim3(64), 0, stream, qkv, bias);
  hipLaunchKernelGGL(k_proj_pm, dim3(1200), dim3(256), 0, stream, qkv, wpb, out);
}

// Round 26
// 234.147 us; speedup vs baseline: 2.2035x; 1.0071x over previous
//
#include <hip/hip_runtime.h>
#include <hip/hip_bf16.h>
#include <math.h>

#define DIM   384
#define HEADS 12
#define HD    32
#define WIN   7
#define NPIX  49
#define IMG   56
#define NPF   3136
#define NWIN  1024

typedef __attribute__((ext_vector_type(8))) short short8;
typedef __attribute__((ext_vector_type(4))) float f32x4;
typedef __attribute__((ext_vector_type(4))) float f4;
typedef __attribute__((ext_vector_type(4))) unsigned short us4;
typedef __attribute__((ext_vector_type(8))) unsigned short us8;
#define MFMA __builtin_amdgcn_mfma_f32_16x16x32_bf16

#define SOFT_BARRIER()                                         \
  do {                                                         \
    asm volatile("s_waitcnt lgkmcnt(0)" ::: "memory");         \
    __builtin_amdgcn_s_barrier();                              \
  } while (0)

__device__ inline ushort tob(float f) {
  unsigned u; __builtin_memcpy(&u, &f, 4);
  u += 0x7fffu + ((u >> 16) & 1u);
  return (ushort)(u >> 16);
}

// ---------------- bias table ----------------
__global__ void k_bias(const float* __restrict__ cpb, float* __restrict__ bias) {
  int idx = blockIdx.x * 256 + threadIdx.x;
  if (idx >= HEADS * NPIX * NPIX) return;
  int m = idx % NPIX;
  int n = (idx / NPIX) % NPIX;
  int h = idx / (NPIX * NPIX);
  int sy = (n / WIN - m / WIN) + (WIN - 1);
  int sx = (n % WIN - m % WIN) + (WIN - 1);
  const double inv_log_beta = 1.0 / log(1.3);
  double fy = (sy == 0 ? 0.0 : log1p((double)sy) * inv_log_beta) + 6.0;
  double fx = (sx == 0 ? 0.0 : log1p((double)sx) * inv_log_beta) + 6.0;
  fy = fmin(12.0, fmax(0.0, fy));
  fx = fmin(12.0, fmax(0.0, fx));
  int ridx = (int)(fy * 13.0 + fx);
  bias[idx] = cpb[ridx * HEADS + h];
}

__global__ void k_rmap(int* __restrict__ rmap) {
  int p = blockIdx.x * 256 + threadIdx.x;
  if (p < NPF) {
    int wb = p / NPIX, n = p - (p / NPIX) * NPIX;
    int gy = wb >> 3, gx = wb & 7;
    int wy = n / WIN, wx = n - (n / WIN) * WIN;
    rmap[p] = ((gy * WIN + wy + 4) % IMG) * IMG + (gx * WIN + wx + 4) % IMG;
  }
}

// ---------------- weights -> bf16 (once) ----------------
__global__ void k_wcvt(const float* __restrict__ wqkv, const float* __restrict__ wproj,
                       ushort* __restrict__ wqb, ushort* __restrict__ wpb) {
  int i = blockIdx.x * 256 + threadIdx.x;
  const int nq = 1152 * DIM / 8;
  const int np = DIM * DIM / 8;
  if (i < nq) {
    f4 a = *(const f4*)&wqkv[i * 8];
    f4 b = *(const f4*)&wqkv[i * 8 + 4];
    us8 u; u[0]=tob(a[0]);u[1]=tob(a[1]);u[2]=tob(a[2]);u[3]=tob(a[3]);
    u[4]=tob(b[0]);u[5]=tob(b[1]);u[6]=tob(b[2]);u[7]=tob(b[3]);
    *(us8*)&wqb[i * 8] = u;
  } else if (i < nq + np) {
    int j = i - nq;
    f4 a = *(const f4*)&wproj[j * 8];
    f4 b = *(const f4*)&wproj[j * 8 + 4];
    us8 u; u[0]=tob(a[0]);u[1]=tob(a[1]);u[2]=tob(a[2]);u[3]=tob(a[3]);
    u[4]=tob(b[0]);u[5]=tob(b[1]);u[6]=tob(b[2]);u[7]=tob(b[3]);
    *(us8*)&wpb[j * 8] = u;
  }
}

// ---------------- x -> xw[b][p'][c] bf16, 6-way channel-split ---------------
__global__ __launch_bounds__(256) void k_xw(const float* __restrict__ x,
                                            const int* __restrict__ rmap,
                                            ushort* __restrict__ xw) {
  int gid = blockIdx.x * 256 + threadIdx.x;   // 16*6*3136 exact
  int p  = gid % NPF;
  int cc = (gid / NPF) % 6;
  int b  = gid / (6 * NPF);
  int sp = rmap[p];
  const float* xs = x + (size_t)b * DIM * NPF + (size_t)(cc * 64) * NPF + sp;
  ushort* xd = xw + ((size_t)b * NPF + p) * DIM + cc * 64;
  for (int c0 = 0; c0 < 64; c0 += 8) {
    us8 u;
#pragma unroll
    for (int i = 0; i < 8; ++i) u[i] = tob(xs[(size_t)(c0 + i) * NPF]);
    *(us8*)&xd[c0] = u;
  }
}

// ---------------- QKV GEMM: 128x128 tile; q/k -> qk[b][p][768], v -> vt ------
__global__ __launch_bounds__(256) void k_qkv_pm(const ushort* __restrict__ xw,
                                                const ushort* __restrict__ wqb,
                                                ushort* __restrict__ qk,
                                                ushort* __restrict__ vt) {
  __shared__ __align__(16) ushort sA[2][128 * 40];
  __shared__ __align__(16) ushort sB[2][128 * 40];
  int t   = threadIdx.x;
  int bid = blockIdx.x;
  int swz = (bid & 7) * 450 + (bid >> 3);   // 3600 = 8*450, bijective
  int o0  = (swz % 9) * 128;
  int pbt = swz / 9;
  int p0  = (pbt % 25) * 128;
  int b   = pbt / 25;

  int lane = t & 63, w = t >> 6;
  int wm = w >> 1, wn = w & 1;
  int l15 = lane & 15, l4 = lane >> 4;

  int ra0 = t >> 2,          ca0 = (t & 3) * 8;
  int ra1 = (t + 256) >> 2,  ca1 = ((t + 256) & 3) * 8;
  const ushort* apt0 = wqb + (size_t)(o0 + ra0) * DIM + ca0;
  const ushort* apt1 = wqb + (size_t)(o0 + ra1) * DIM + ca1;
  int pr0 = p0 + ra0; if (pr0 >= NPF) pr0 = NPF - 1;
  int pr1 = p0 + ra1; if (pr1 >= NPF) pr1 = NPF - 1;
  const ushort* bpt0 = xw + ((size_t)b * NPF + pr0) * DIM + ca0;
  const ushort* bpt1 = xw + ((size_t)b * NPF + pr1) * DIM + ca1;

  struct Stage { us8 a0, a1, b0, b1; };
  Stage st0, st1;

#define QLOAD(S, K0)                                    \
  do {                                                  \
    (S).a0 = *(const us8*)&apt0[(K0)];                  \
    (S).a1 = *(const us8*)&apt1[(K0)];                  \
    (S).b0 = *(const us8*)&bpt0[(K0)];                  \
    (S).b1 = *(const us8*)&bpt1[(K0)];                  \
  } while (0)
#define QWRITE(S, BUF)                                  \
  do {                                                  \
    *(us8*)&sA[(BUF)][ra0 * 40 + ca0] = (S).a0;         \
    *(us8*)&sA[(BUF)][ra1 * 40 + ca1] = (S).a1;         \
    *(us8*)&sB[(BUF)][ra0 * 40 + ca0] = (S).b0;         \
    *(us8*)&sB[(BUF)][ra1 * 40 + ca1] = (S).b1;         \
  } while (0)

  f32x4 acc[4][4] = {};

  QLOAD(st0, 0);
  QWRITE(st0, 0);
  QLOAD(st1, 32);

#pragma unroll
  for (int ks = 0; ks < 12; ++ks) {
    SOFT_BARRIER();
    if (ks < 10) {
      if ((ks & 1) == 0) QLOAD(st0, (ks + 2) * 32);
      else               QLOAD(st1, (ks + 2) * 32);
    }
    int cur = ks & 1;
    short8 af[4], bfr[4];
#pragma unroll
    for (int mi = 0; mi < 4; ++mi)
      af[mi] = *(const short8*)&sA[cur][(wm * 64 + mi * 16 + l15) * 40 + l4 * 8];
#pragma unroll
    for (int ni = 0; ni < 4; ++ni)
      bfr[ni] = *(const short8*)&sB[cur][(wn * 64 + ni * 16 + l15) * 40 + l4 * 8];
#pragma unroll
    for (int mi = 0; mi < 4; ++mi)
#pragma unroll
      for (int ni = 0; ni < 4; ++ni)
        acc[mi][ni] = MFMA(af[mi], bfr[ni], acc[mi][ni], 0, 0, 0);
    if (ks < 11) {
      if ((ks & 1) == 0) QWRITE(st1, 1);
      else               QWRITE(st0, 0);
    }
  }
#undef QLOAD
#undef QWRITE

  if (o0 < 768) {
    // q/k part: pixel-major rows of 768 channels
#pragma unroll
    for (int mi = 0; mi < 4; ++mi)
#pragma unroll
      for (int ni = 0; ni < 4; ++ni) {
        int p = p0 + wn * 64 + ni * 16 + l15;
        if (p < NPF) {
          us4 u;
#pragma unroll
          for (int r = 0; r < 4; ++r) u[r] = tob(acc[mi][ni][r]);
          *(us4*)&qk[((size_t)b * NPF + p) * 768 + o0 + wm * 64 + mi * 16 + (l4 << 2)] = u;
        }
      }
  } else {
    // v part: channel-major vt[b][c][p]
    int c0 = o0 - 768 + wm * 64;
#pragma unroll
    for (int mi = 0; mi < 4; ++mi)
#pragma unroll
      for (int ni = 0; ni < 4; ++ni) {
        int p = p0 + wn * 64 + ni * 16 + l15;
        if (p < NPF) {
#pragma unroll
          for (int r = 0; r < 4; ++r) {
            int c = c0 + mi * 16 + (l4 << 2) + r;
            vt[((size_t)b * DIM + c) * NPF + p] = tob(acc[mi][ni][r]);
          }
        }
      }
  }
}

// ---------------- attention: V^T contiguous from vt; LDS = pa only ----------
__global__ __launch_bounds__(64) void k_attn_pm(ushort* __restrict__ qk,
                                                const ushort* __restrict__ vt,
                                                const float* __restrict__ bias) {
  __shared__ __align__(16) ushort pa[64 * 72];   // 9216 B

  int t = threadIdx.x;
  int bid = blockIdx.x;
  int swz = (bid & 7) * 1536 + (bid >> 3);   // 12288 = 8*1536
  int h = swz % HEADS, wb = swz / HEADS;
  int b = wb >> 6;
  int w49 = (wb & 63) * NPIX;
  ushort* qrow = qk + ((size_t)b * NPF + w49) * 768 + h * HD;
  const ushort* vrow = vt + ((size_t)b * DIM + h * HD) * NPF + w49;

  int l15 = t & 15, l4 = t >> 4;

  short8 af[4], bfr[4];
#pragma unroll
  for (int mi = 0; mi < 4; ++mi) {
    int rq = mi * 16 + l15; if (rq > 48) rq = 48;
    af[mi] = *(const short8*)&qrow[(size_t)rq * 768 + l4 * 8];
  }
#pragma unroll
  for (int ni = 0; ni < 4; ++ni) {
    int rk = ni * 16 + l15; if (rk > 48) rk = 48;
    bfr[ni] = *(const short8*)&qrow[(size_t)rk * 768 + DIM + l4 * 8];
  }
  f32x4 acc[4][4] = {};
#pragma unroll
  for (int mi = 0; mi < 4; ++mi)
#pragma unroll
    for (int ni = 0; ni < 4; ++ni)
      acc[mi][ni] = MFMA(af[mi], bfr[ni], acc[mi][ni], 0, 0, 0);

  // V fragments: contiguous us8 from vt (tail m>=49 reads pad into xw; P=0)
  short8 vf[2][2];
#pragma unroll
  for (int ks = 0; ks < 2; ++ks)
#pragma unroll
    for (int nd = 0; nd < 2; ++nd)
      vf[ks][nd] = *(const short8*)&vrow[(size_t)(nd * 16 + l15) * NPF + ks * 32 + l4 * 8];

  const float scale = 0.17677669529663687f;
  const float* bh = bias + h * NPIX * NPIX;
  float mx[16], sm[16];
#pragma unroll
  for (int mi = 0; mi < 4; ++mi)
#pragma unroll
    for (int r = 0; r < 4; ++r) {
      int n = mi * 16 + (l4 << 2) + r;
      float vmax = -3e38f;
#pragma unroll
      for (int ni = 0; ni < 4; ++ni) {
        int m = ni * 16 + l15;
        float s = (m < NPIX)
                    ? acc[mi][ni][r] * scale + ((n < NPIX) ? bh[n * NPIX + m] : 0.f)
                    : -3e38f;
        acc[mi][ni][r] = s;
        vmax = fmaxf(vmax, s);
      }
      mx[mi * 4 + r] = vmax;
    }
#pragma unroll
  for (int i = 1; i < 16; i <<= 1)
#pragma unroll
    for (int j = 0; j < 16; ++j) mx[j] = fmaxf(mx[j], __shfl_xor(mx[j], i));
#pragma unroll
  for (int mi = 0; mi < 4; ++mi)
#pragma unroll
    for (int r = 0; r < 4; ++r) {
      float s = 0.f;
#pragma unroll
      for (int ni = 0; ni < 4; ++ni) {
        float e = expf(acc[mi][ni][r] - mx[mi * 4 + r]);
        acc[mi][ni][r] = e;
        s += e;
      }
      sm[mi * 4 + r] = s;
    }
#pragma unroll
  for (int i = 1; i < 16; i <<= 1)
#pragma unroll
    for (int j = 0; j < 16; ++j) sm[j] += __shfl_xor(sm[j], i);

#pragma unroll
  for (int mi = 0; mi < 4; ++mi)
#pragma unroll
    for (int r = 0; r < 4; ++r) {
      float ri = 1.f / sm[mi * 4 + r];
      int n = mi * 16 + (l4 << 2) + r;
#pragma unroll
      for (int ni = 0; ni < 4; ++ni)
        pa[n * 72 + ni * 16 + l15] = tob(acc[mi][ni][r] * ri);
    }

  f32x4 yac[4][2] = {};
#pragma unroll
  for (int ks = 0; ks < 2; ++ks) {
    short8 pf[4];
#pragma unroll
    for (int mi = 0; mi < 4; ++mi) pf[mi] = *(const short8*)&pa[(mi * 16 + l15) * 72 + ks * 32 + l4 * 8];
#pragma unroll
    for (int mi = 0; mi < 4; ++mi)
#pragma unroll
      for (int nd = 0; nd < 2; ++nd)
        yac[mi][nd] = MFMA(pf[mi], vf[ks][nd], yac[mi][nd], 0, 0, 0);
  }
#pragma unroll
  for (int mi = 0; mi < 4; ++mi)
#pragma unroll
    for (int nd = 0; nd < 2; ++nd) {
      int nb = mi * 16 + (l4 << 2);
      int d = nd * 16 + l15;
#pragma unroll
      for (int r = 0; r < 4; ++r)
        if (nb + r < NPIX) qrow[(size_t)(nb + r) * 768 + d] = tob(yac[mi][nd][r]);
    }
}

// ---------------- proj GEMM: Y from qk (stride 768) -------------------------
__global__ __launch_bounds__(256) void k_proj_pm(const ushort* __restrict__ qk,
                                                 const ushort* __restrict__ wpb,
                                                 float* __restrict__ out) {
  __shared__ __align__(16) ushort sA[2][128 * 40];
  __shared__ __align__(16) ushort sB[2][128 * 40];
  __shared__ int srm[128];
  int t   = threadIdx.x;
  int bid = blockIdx.x;
  int swz = (bid & 7) * 150 + (bid >> 3);   // 1200 = 8*150
  int o0  = (swz % 3) * 128;
  int pb  = swz / 3;
  int p0  = (pb % 25) * 128;
  int b   = pb / 25;
  if (t < 128) {
    int pg = p0 + t;
    if (pg >= NPF) pg = 0;
    int si = (pg / IMG + 53) % IMG, sj = (pg % IMG + 53) % IMG;
    srm[t] = ((si / WIN) * 8 + sj / WIN) * NPIX + (si % WIN) * WIN + (sj % WIN);
  }
  __syncthreads();

  int lane = t & 63, w = t >> 6;
  int wm = w >> 1, wn = w & 1;
  int l15 = lane & 15, l4 = lane >> 4;

  int ra0 = t >> 2,          ca0 = (t & 3) * 8;
  int ra1 = (t + 256) >> 2,  ca1 = ((t + 256) & 3) * 8;
  const ushort* apt0 = wpb + (size_t)(o0 + ra0) * DIM + ca0;
  const ushort* apt1 = wpb + (size_t)(o0 + ra1) * DIM + ca1;
  const ushort* bpt0 = qk + ((size_t)b * NPF + srm[ra0]) * 768 + ca0;
  const ushort* bpt1 = qk + ((size_t)b * NPF + srm[ra1]) * 768 + ca1;

  struct Stage { us8 a0, a1, b0, b1; };
  Stage st0, st1;

#define PLOAD(S, K0)                                    \
  do {                                                  \
    (S).a0 = *(const us8*)&apt0[(K0)];                  \
    (S).a1 = *(const us8*)&apt1[(K0)];                  \
    (S).b0 = *(const us8*)&bpt0[(K0)];                  \
    (S).b1 = *(const us8*)&bpt1[(K0)];                  \
  } while (0)
#define PWRITE(S, BUF)                                  \
  do {                                                  \
    *(us8*)&sA[(BUF)][ra0 * 40 + ca0] = (S).a0;         \
    *(us8*)&sA[(BUF)][ra1 * 40 + ca1] = (S).a1;         \
    *(us8*)&sB[(BUF)][ra0 * 40 + ca0] = (S).b0;         \
    *(us8*)&sB[(BUF)][ra1 * 40 + ca1] = (S).b1;         \
  } while (0)

  f32x4 acc[4][4] = {};

  PLOAD(st0, 0);
  PWRITE(st0, 0);
  PLOAD(st1, 32);

#pragma unroll
  for (int ks = 0; ks < 12; ++ks) {
    SOFT_BARRIER();
    if (ks < 10) {
      if ((ks & 1) == 0) PLOAD(st0, (ks + 2) * 32);
      else               PLOAD(st1, (ks + 2) * 32);
    }
    int cur = ks & 1;
    short8 af[4], bfr[4];
#pragma unroll
    for (int mi = 0; mi < 4; ++mi)
      af[mi] = *(const short8*)&sA[cur][(wm * 64 + mi * 16 + l15) * 40 + l4 * 8];
#pragma unroll
    for (int ni = 0; ni < 4; ++ni)
      bfr[ni] = *(const short8*)&sB[cur][(wn * 64 + ni * 16 + l15) * 40 + l4 * 8];
#pragma unroll
    for (int mi = 0; mi < 4; ++mi)
#pragma unroll
      for (int ni = 0; ni < 4; ++ni)
        acc[mi][ni] = MFMA(af[mi], bfr[ni], acc[mi][ni], 0, 0, 0);
    if (ks < 11) {
      if ((ks & 1) == 0) PWRITE(st1, 1);
      else               PWRITE(st0, 0);
    }
  }
#undef PLOAD
#undef PWRITE

  for (int mi = 0; mi < 4; ++mi)
    for (int ni = 0; ni < 4; ++ni)
      for (int r = 0; r < 4; ++r) {
        int o = o0 + wm * 64 + mi * 16 + (l4 << 2) + r;
        int p = p0 + wn * 64 + ni * 16 + l15;
        if (p < NPF)
          out[((size_t)b * DIM + o) * NPF + p] = acc[mi][ni][r];
      }
}

extern "C" void kernel_launch(void* const* d_in, const int* in_sizes, int n_in,
                              void* d_out, int out_size, void* d_ws, size_t ws_size,
                              hipStream_t stream) {
  const float* x     = (const float*)d_in[0];
  const float* wqkv  = (const float*)d_in[1];
  const float* wproj = (const float*)d_in[2];
  const float* cpb   = (const float*)d_in[3];
  float* out = (float*)d_out;

  char* ws = (char*)d_ws;
  float* bias = (float*)ws;                       // 115248 B
  int*   rmap = (int*)(ws + 115712);              // -> 131072
  ushort* wqb = (ushort*)(ws + 131072);           // 884736 B
  ushort* wpb = (ushort*)(ws + 1015808);          // 294912 B -> 1310720
  const size_t QK_B = (size_t)16 * NPF * 768 * 2; // 77,070,336
  const size_t VT_B = (size_t)16 * DIM * NPF * 2; // 38,535,168
  ushort* qk = (ushort*)(ws + 1310720);
  ushort* vt = (ushort*)(ws + 1310720 + QK_B);
  ushort* xw = (ushort*)(ws + 1310720 + QK_B + VT_B);  // ends 155,451,392 (proven)

  hipLaunchKernelGGL(k_bias, dim3(113), dim3(256), 0, stream, cpb, bias);
  hipLaunchKernelGGL(k_rmap, dim3(13), dim3(256), 0, stream, rmap);
  hipLaunchKernelGGL(k_wcvt, dim3(288), dim3(256), 0, stream, wqkv, wproj, wqb, wpb);
  hipLaunchKernelGGL(k_xw, dim3(1176), dim3(256), 0, stream, x, rmap, xw);
  hipLaunchKernelGGL(k_qkv_pm, dim3(3600), dim3(256), 0, stream, xw, wqb, qk, vt);
  hipLaunchKernelGGL(k_attn_pm, dim3(NWIN * HEADS), dim3(64), 0, stream, qk, vt, bias);
  hipLaunchKernelGGL(k_proj_pm, dim3(1200), dim3(256), 0, stream, qk, wpb, out);
}

// Round 27
// 229.210 us; speedup vs baseline: 2.2510x; 1.0215x over previous
//
#include <hip/hip_runtime.h>
#include <hip/hip_bf16.h>
#include <math.h>

#define DIM   384
#define HEADS 12
#define HD    32
#define WIN   7
#define NPIX  49
#define IMG   56
#define NPF   3136
#define NWIN  1024

typedef __attribute__((ext_vector_type(8))) short short8;
typedef __attribute__((ext_vector_type(4))) float f32x4;
typedef __attribute__((ext_vector_type(4))) float f4;
typedef __attribute__((ext_vector_type(4))) unsigned short us4;
typedef __attribute__((ext_vector_type(8))) unsigned short us8;
#define MFMA __builtin_amdgcn_mfma_f32_16x16x32_bf16

#define SOFT_BARRIER()                                         \
  do {                                                         \
    asm volatile("s_waitcnt lgkmcnt(0)" ::: "memory");         \
    __builtin_amdgcn_s_barrier();                              \
  } while (0)

__device__ inline ushort tob(float f) {
  unsigned u; __builtin_memcpy(&u, &f, 4);
  u += 0x7fffu + ((u >> 16) & 1u);
  return (ushort)(u >> 16);
}

// ---------------- bias table ----------------
__global__ void k_bias(const float* __restrict__ cpb, float* __restrict__ bias) {
  int idx = blockIdx.x * 256 + threadIdx.x;
  if (idx >= HEADS * NPIX * NPIX) return;
  int m = idx % NPIX;
  int n = (idx / NPIX) % NPIX;
  int h = idx / (NPIX * NPIX);
  int sy = (n / WIN - m / WIN) + (WIN - 1);
  int sx = (n % WIN - m % WIN) + (WIN - 1);
  const double inv_log_beta = 1.0 / log(1.3);
  double fy = (sy == 0 ? 0.0 : log1p((double)sy) * inv_log_beta) + 6.0;
  double fx = (sx == 0 ? 0.0 : log1p((double)sx) * inv_log_beta) + 6.0;
  fy = fmin(12.0, fmax(0.0, fy));
  fx = fmin(12.0, fmax(0.0, fx));
  int ridx = (int)(fy * 13.0 + fx);
  bias[idx] = cpb[ridx * HEADS + h];
}

__global__ void k_rmap(int* __restrict__ rmap) {
  int p = blockIdx.x * 256 + threadIdx.x;
  if (p < NPF) {
    int wb = p / NPIX, n = p - (p / NPIX) * NPIX;
    int gy = wb >> 3, gx = wb & 7;
    int wy = n / WIN, wx = n - (n / WIN) * WIN;
    rmap[p] = ((gy * WIN + wy + 4) % IMG) * IMG + (gx * WIN + wx + 4) % IMG;
  }
}

// ---------------- weights -> bf16 (once) ----------------
__global__ void k_wcvt(const float* __restrict__ wqkv, const float* __restrict__ wproj,
                       ushort* __restrict__ wqb, ushort* __restrict__ wpb) {
  int i = blockIdx.x * 256 + threadIdx.x;
  const int nq = 1152 * DIM / 8;
  const int np = DIM * DIM / 8;
  if (i < nq) {
    f4 a = *(const f4*)&wqkv[i * 8];
    f4 b = *(const f4*)&wqkv[i * 8 + 4];
    us8 u; u[0]=tob(a[0]);u[1]=tob(a[1]);u[2]=tob(a[2]);u[3]=tob(a[3]);
    u[4]=tob(b[0]);u[5]=tob(b[1]);u[6]=tob(b[2]);u[7]=tob(b[3]);
    *(us8*)&wqb[i * 8] = u;
  } else if (i < nq + np) {
    int j = i - nq;
    f4 a = *(const f4*)&wproj[j * 8];
    f4 b = *(const f4*)&wproj[j * 8 + 4];
    us8 u; u[0]=tob(a[0]);u[1]=tob(a[1]);u[2]=tob(a[2]);u[3]=tob(a[3]);
    u[4]=tob(b[0]);u[5]=tob(b[1]);u[6]=tob(b[2]);u[7]=tob(b[3]);
    *(us8*)&wpb[j * 8] = u;
  }
}

// ---------------- x -> xw[b][p'][c] bf16, 6-way channel-split ---------------
__global__ __launch_bounds__(256) void k_xw(const float* __restrict__ x,
                                            const int* __restrict__ rmap,
                                            ushort* __restrict__ xw) {
  int gid = blockIdx.x * 256 + threadIdx.x;   // 16*6*3136 exact
  int p  = gid % NPF;
  int cc = (gid / NPF) % 6;
  int b  = gid / (6 * NPF);
  int sp = rmap[p];
  const float* xs = x + (size_t)b * DIM * NPF + (size_t)(cc * 64) * NPF + sp;
  ushort* xd = xw + ((size_t)b * NPF + p) * DIM + cc * 64;
  for (int c0 = 0; c0 < 64; c0 += 8) {
    us8 u;
#pragma unroll
    for (int i = 0; i < 8; ++i) u[i] = tob(xs[(size_t)(c0 + i) * NPF]);
    *(us8*)&xd[c0] = u;
  }
}

// ---------------- QKV GEMM: 128x128 tile; q/k -> qk[b][p][768], v -> vt ------
__global__ __launch_bounds__(256) void k_qkv_pm(const ushort* __restrict__ xw,
                                                const ushort* __restrict__ wqb,
                                                ushort* __restrict__ qk,
                                                ushort* __restrict__ vt) {
  __shared__ __align__(16) ushort sA[2][128 * 40];
  __shared__ __align__(16) ushort sB[2][128 * 40];
  int t   = threadIdx.x;
  int bid = blockIdx.x;
  int swz = (bid & 7) * 450 + (bid >> 3);   // 3600 = 8*450, bijective
  int o0  = (swz % 9) * 128;
  int pbt = swz / 9;
  int p0  = (pbt % 25) * 128;
  int b   = pbt / 25;

  int lane = t & 63, w = t >> 6;
  int wm = w >> 1, wn = w & 1;
  int l15 = lane & 15, l4 = lane >> 4;

  int ra0 = t >> 2,          ca0 = (t & 3) * 8;
  int ra1 = (t + 256) >> 2,  ca1 = ((t + 256) & 3) * 8;
  const ushort* apt0 = wqb + (size_t)(o0 + ra0) * DIM + ca0;
  const ushort* apt1 = wqb + (size_t)(o0 + ra1) * DIM + ca1;
  int pr0 = p0 + ra0; if (pr0 >= NPF) pr0 = NPF - 1;
  int pr1 = p0 + ra1; if (pr1 >= NPF) pr1 = NPF - 1;
  const ushort* bpt0 = xw + ((size_t)b * NPF + pr0) * DIM + ca0;
  const ushort* bpt1 = xw + ((size_t)b * NPF + pr1) * DIM + ca1;

  struct Stage { us8 a0, a1, b0, b1; };
  Stage st0, st1;

#define QLOAD(S, K0)                                    \
  do {                                                  \
    (S).a0 = *(const us8*)&apt0[(K0)];                  \
    (S).a1 = *(const us8*)&apt1[(K0)];                  \
    (S).b0 = *(const us8*)&bpt0[(K0)];                  \
    (S).b1 = *(const us8*)&bpt1[(K0)];                  \
  } while (0)
#define QWRITE(S, BUF)                                  \
  do {                                                  \
    *(us8*)&sA[(BUF)][ra0 * 40 + ca0] = (S).a0;         \
    *(us8*)&sA[(BUF)][ra1 * 40 + ca1] = (S).a1;         \
    *(us8*)&sB[(BUF)][ra0 * 40 + ca0] = (S).b0;         \
    *(us8*)&sB[(BUF)][ra1 * 40 + ca1] = (S).b1;         \
  } while (0)

  f32x4 acc[4][4] = {};

  QLOAD(st0, 0);
  QWRITE(st0, 0);
  QLOAD(st1, 32);

#pragma unroll
  for (int ks = 0; ks < 12; ++ks) {
    SOFT_BARRIER();
    if (ks < 10) {
      if ((ks & 1) == 0) QLOAD(st0, (ks + 2) * 32);
      else               QLOAD(st1, (ks + 2) * 32);
    }
    int cur = ks & 1;
    short8 af[4], bfr[4];
#pragma unroll
    for (int mi = 0; mi < 4; ++mi)
      af[mi] = *(const short8*)&sA[cur][(wm * 64 + mi * 16 + l15) * 40 + l4 * 8];
#pragma unroll
    for (int ni = 0; ni < 4; ++ni)
      bfr[ni] = *(const short8*)&sB[cur][(wn * 64 + ni * 16 + l15) * 40 + l4 * 8];
#pragma unroll
    for (int mi = 0; mi < 4; ++mi)
#pragma unroll
      for (int ni = 0; ni < 4; ++ni)
        acc[mi][ni] = MFMA(af[mi], bfr[ni], acc[mi][ni], 0, 0, 0);
    if (ks < 11) {
      if ((ks & 1) == 0) QWRITE(st1, 1);
      else               QWRITE(st0, 0);
    }
  }
#undef QLOAD
#undef QWRITE

  if (o0 < 768) {
#pragma unroll
    for (int mi = 0; mi < 4; ++mi)
#pragma unroll
      for (int ni = 0; ni < 4; ++ni) {
        int p = p0 + wn * 64 + ni * 16 + l15;
        if (p < NPF) {
          us4 u;
#pragma unroll
          for (int r = 0; r < 4; ++r) u[r] = tob(acc[mi][ni][r]);
          *(us4*)&qk[((size_t)b * NPF + p) * 768 + o0 + wm * 64 + mi * 16 + (l4 << 2)] = u;
        }
      }
  } else {
    int c0 = o0 - 768 + wm * 64;
#pragma unroll
    for (int mi = 0; mi < 4; ++mi)
#pragma unroll
      for (int ni = 0; ni < 4; ++ni) {
        int p = p0 + wn * 64 + ni * 16 + l15;
        if (p < NPF) {
#pragma unroll
          for (int r = 0; r < 4; ++r) {
            int c = c0 + mi * 16 + (l4 << 2) + r;
            vt[((size_t)b * DIM + c) * NPF + p] = tob(acc[mi][ni][r]);
          }
        }
      }
  }
}

// ---------------- attention: 4 heads/block (wave=head), no-max softmax ------
__global__ __launch_bounds__(256) void k_attn_pm(ushort* __restrict__ qk,
                                                 const ushort* __restrict__ vt,
                                                 const float* __restrict__ bias) {
  __shared__ __align__(16) ushort pab[4][64 * 72];   // 36864 B

  int t = threadIdx.x;
  int lane = t & 63, wv = t >> 6;
  int bid = blockIdx.x;
  int swz = (bid & 7) * 384 + (bid >> 3);   // 3072 = 8*384, bijective
  int hg = swz % 3, wb = swz / 3;
  int h = hg * 4 + wv;
  int b = wb >> 6;
  int w49 = (wb & 63) * NPIX;
  ushort* qrow = qk + ((size_t)b * NPF + w49) * 768 + h * HD;
  const ushort* vrow = vt + ((size_t)b * DIM + h * HD) * NPF + w49;
  ushort* pa = pab[wv];

  int l15 = lane & 15, l4 = lane >> 4;

  short8 af[4], bfr[4];
#pragma unroll
  for (int mi = 0; mi < 4; ++mi) {
    int rq = mi * 16 + l15; if (rq > 48) rq = 48;
    af[mi] = *(const short8*)&qrow[(size_t)rq * 768 + l4 * 8];
  }
#pragma unroll
  for (int ni = 0; ni < 4; ++ni) {
    int rk = ni * 16 + l15; if (rk > 48) rk = 48;
    bfr[ni] = *(const short8*)&qrow[(size_t)rk * 768 + DIM + l4 * 8];
  }
  f32x4 acc[4][4] = {};
#pragma unroll
  for (int mi = 0; mi < 4; ++mi)
#pragma unroll
    for (int ni = 0; ni < 4; ++ni)
      acc[mi][ni] = MFMA(af[mi], bfr[ni], acc[mi][ni], 0, 0, 0);

  // V fragments: contiguous us8 from vt (tail m>=49 harmless: P=0)
  short8 vf[2][2];
#pragma unroll
  for (int ks = 0; ks < 2; ++ks)
#pragma unroll
    for (int nd = 0; nd < 2; ++nd)
      vf[ks][nd] = *(const short8*)&vrow[(size_t)(nd * 16 + l15) * NPF + ks * 32 + l4 * 8];

  // no-max softmax: P = exp(s)/sum(exp(s)); rows n>=49 give NaN, discarded
  const float scale = 0.17677669529663687f;
  const float* bh = bias + h * NPIX * NPIX;
  float sm[16];
#pragma unroll
  for (int mi = 0; mi < 4; ++mi)
#pragma unroll
    for (int r = 0; r < 4; ++r) {
      int n = mi * 16 + (l4 << 2) + r;
      float s = 0.f;
#pragma unroll
      for (int ni = 0; ni < 4; ++ni) {
        int m = ni * 16 + l15;
        float e = (m < NPIX && n < NPIX)
                    ? expf(acc[mi][ni][r] * scale + bh[n * NPIX + m])
                    : 0.f;
        acc[mi][ni][r] = e;
        s += e;
      }
      sm[mi * 4 + r] = s;
    }
#pragma unroll
  for (int i = 1; i < 16; i <<= 1)
#pragma unroll
    for (int j = 0; j < 16; ++j) sm[j] += __shfl_xor(sm[j], i);

#pragma unroll
  for (int mi = 0; mi < 4; ++mi)
#pragma unroll
    for (int r = 0; r < 4; ++r) {
      float ri = 1.f / sm[mi * 4 + r];
      int n = mi * 16 + (l4 << 2) + r;
#pragma unroll
      for (int ni = 0; ni < 4; ++ni)
        pa[n * 72 + ni * 16 + l15] = tob(acc[mi][ni][r] * ri);
    }

  f32x4 yac[4][2] = {};
#pragma unroll
  for (int ks = 0; ks < 2; ++ks) {
    short8 pf[4];
#pragma unroll
    for (int mi = 0; mi < 4; ++mi) pf[mi] = *(const short8*)&pa[(mi * 16 + l15) * 72 + ks * 32 + l4 * 8];
#pragma unroll
    for (int mi = 0; mi < 4; ++mi)
#pragma unroll
      for (int nd = 0; nd < 2; ++nd)
        yac[mi][nd] = MFMA(pf[mi], vf[ks][nd], yac[mi][nd], 0, 0, 0);
  }

  // Y: stage into pa (P dead), then coalesced us8 row stores
#pragma unroll
  for (int mi = 0; mi < 4; ++mi)
#pragma unroll
    for (int nd = 0; nd < 2; ++nd)
#pragma unroll
      for (int r = 0; r < 4; ++r)
        pa[(mi * 16 + (l4 << 2) + r) * 72 + nd * 16 + l15] = tob(yac[mi][nd][r]);
  asm volatile("s_waitcnt lgkmcnt(0)" ::: "memory");
  if (lane < NPIX) {
#pragma unroll
    for (int s = 0; s < 4; ++s)
      *(us8*)&qrow[(size_t)lane * 768 + s * 8] = *(const us8*)&pa[lane * 72 + s * 8];
  }
}

// ---------------- proj GEMM: Y from qk (stride 768) -------------------------
__global__ __launch_bounds__(256) void k_proj_pm(const ushort* __restrict__ qk,
                                                 const ushort* __restrict__ wpb,
                                                 float* __restrict__ out) {
  __shared__ __align__(16) ushort sA[2][128 * 40];
  __shared__ __align__(16) ushort sB[2][128 * 40];
  __shared__ int srm[128];
  int t   = threadIdx.x;
  int bid = blockIdx.x;
  int swz = (bid & 7) * 150 + (bid >> 3);   // 1200 = 8*150
  int o0  = (swz % 3) * 128;
  int pb  = swz / 3;
  int p0  = (pb % 25) * 128;
  int b   = pb / 25;
  if (t < 128) {
    int pg = p0 + t;
    if (pg >= NPF) pg = 0;
    int si = (pg / IMG + 53) % IMG, sj = (pg % IMG + 53) % IMG;
    srm[t] = ((si / WIN) * 8 + sj / WIN) * NPIX + (si % WIN) * WIN + (sj % WIN);
  }
  __syncthreads();

  int lane = t & 63, w = t >> 6;
  int wm = w >> 1, wn = w & 1;
  int l15 = lane & 15, l4 = lane >> 4;

  int ra0 = t >> 2,          ca0 = (t & 3) * 8;
  int ra1 = (t + 256) >> 2,  ca1 = ((t + 256) & 3) * 8;
  const ushort* apt0 = wpb + (size_t)(o0 + ra0) * DIM + ca0;
  const ushort* apt1 = wpb + (size_t)(o0 + ra1) * DIM + ca1;
  const ushort* bpt0 = qk + ((size_t)b * NPF + srm[ra0]) * 768 + ca0;
  const ushort* bpt1 = qk + ((size_t)b * NPF + srm[ra1]) * 768 + ca1;

  struct Stage { us8 a0, a1, b0, b1; };
  Stage st0, st1;

#define PLOAD(S, K0)                                    \
  do {                                                  \
    (S).a0 = *(const us8*)&apt0[(K0)];                  \
    (S).a1 = *(const us8*)&apt1[(K0)];                  \
    (S).b0 = *(const us8*)&bpt0[(K0)];                  \
    (S).b1 = *(const us8*)&bpt1[(K0)];                  \
  } while (0)
#define PWRITE(S, BUF)                                  \
  do {                                                  \
    *(us8*)&sA[(BUF)][ra0 * 40 + ca0] = (S).a0;         \
    *(us8*)&sA[(BUF)][ra1 * 40 + ca1] = (S).a1;         \
    *(us8*)&sB[(BUF)][ra0 * 40 + ca0] = (S).b0;         \
    *(us8*)&sB[(BUF)][ra1 * 40 + ca1] = (S).b1;         \
  } while (0)

  f32x4 acc[4][4] = {};

  PLOAD(st0, 0);
  PWRITE(st0, 0);
  PLOAD(st1, 32);

#pragma unroll
  for (int ks = 0; ks < 12; ++ks) {
    SOFT_BARRIER();
    if (ks < 10) {
      if ((ks & 1) == 0) PLOAD(st0, (ks + 2) * 32);
      else               PLOAD(st1, (ks + 2) * 32);
    }
    int cur = ks & 1;
    short8 af[4], bfr[4];
#pragma unroll
    for (int mi = 0; mi < 4; ++mi)
      af[mi] = *(const short8*)&sA[cur][(wm * 64 + mi * 16 + l15) * 40 + l4 * 8];
#pragma unroll
    for (int ni = 0; ni < 4; ++ni)
      bfr[ni] = *(const short8*)&sB[cur][(wn * 64 + ni * 16 + l15) * 40 + l4 * 8];
#pragma unroll
    for (int mi = 0; mi < 4; ++mi)
#pragma unroll
      for (int ni = 0; ni < 4; ++ni)
        acc[mi][ni] = MFMA(af[mi], bfr[ni], acc[mi][ni], 0, 0, 0);
    if (ks < 11) {
      if ((ks & 1) == 0) PWRITE(st1, 1);
      else               PWRITE(st0, 0);
    }
  }
#undef PLOAD
#undef PWRITE

  for (int mi = 0; mi < 4; ++mi)
    for (int ni = 0; ni < 4; ++ni)
      for (int r = 0; r < 4; ++r) {
        int o = o0 + wm * 64 + mi * 16 + (l4 << 2) + r;
        int p = p0 + wn * 64 + ni * 16 + l15;
        if (p < NPF)
          out[((size_t)b * DIM + o) * NPF + p] = acc[mi][ni][r];
      }
}

extern "C" void kernel_launch(void* const* d_in, const int* in_sizes, int n_in,
                              void* d_out, int out_size, void* d_ws, size_t ws_size,
                              hipStream_t stream) {
  const float* x     = (const float*)d_in[0];
  const float* wqkv  = (const float*)d_in[1];
  const float* wproj = (const float*)d_in[2];
  const float* cpb   = (const float*)d_in[3];
  float* out = (float*)d_out;

  char* ws = (char*)d_ws;
  float* bias = (float*)ws;                       // 115248 B
  int*   rmap = (int*)(ws + 115712);              // -> 131072
  ushort* wqb = (ushort*)(ws + 131072);           // 884736 B
  ushort* wpb = (ushort*)(ws + 1015808);          // 294912 B -> 1310720
  const size_t QK_B = (size_t)16 * NPF * 768 * 2; // 77,070,336
  const size_t VT_B = (size_t)16 * DIM * NPF * 2; // 38,535,168
  ushort* qk = (ushort*)(ws + 1310720);
  ushort* vt = (ushort*)(ws + 1310720 + QK_B);
  ushort* xw = (ushort*)(ws + 1310720 + QK_B + VT_B);  // ends 155,451,392 (proven)

  hipLaunchKernelGGL(k_bias, dim3(113), dim3(256), 0, stream, cpb, bias);
  hipLaunchKernelGGL(k_rmap, dim3(13), dim3(256), 0, stream, rmap);
  hipLaunchKernelGGL(k_wcvt, dim3(288), dim3(256), 0, stream, wqkv, wproj, wqb, wpb);
  hipLaunchKernelGGL(k_xw, dim3(1176), dim3(256), 0, stream, x, rmap, xw);
  hipLaunchKernelGGL(k_qkv_pm, dim3(3600), dim3(256), 0, stream, xw, wqb, qk, vt);
  hipLaunchKernelGGL(k_attn_pm, dim3(3072), dim3(256), 0, stream, qk, vt, bias);
  hipLaunchKernelGGL(k_proj_pm, dim3(1200), dim3(256), 0, stream, qk, wpb, out);
}

// Round 28
// 225.358 us; speedup vs baseline: 2.2895x; 1.0171x over previous
//
#include <hip/hip_runtime.h>
#include <hip/hip_bf16.h>
#include <math.h>

#define DIM   384
#define HEADS 12
#define HD    32
#define WIN   7
#define NPIX  49
#define IMG   56
#define NPF   3136
#define NWIN  1024

typedef __attribute__((ext_vector_type(8))) short short8;
typedef __attribute__((ext_vector_type(4))) float f32x4;
typedef __attribute__((ext_vector_type(4))) float f4;
typedef __attribute__((ext_vector_type(4))) unsigned short us4;
typedef __attribute__((ext_vector_type(8))) unsigned short us8;
#define MFMA __builtin_amdgcn_mfma_f32_16x16x32_bf16

#define SOFT_BARRIER()                                         \
  do {                                                         \
    asm volatile("s_waitcnt lgkmcnt(0)" ::: "memory");         \
    __builtin_amdgcn_s_barrier();                              \
  } while (0)

__device__ inline ushort tob(float f) {
  unsigned u; __builtin_memcpy(&u, &f, 4);
  u += 0x7fffu + ((u >> 16) & 1u);
  return (ushort)(u >> 16);
}

// ---------------- bias table (pre-scaled by log2(e) for exp2-softmax) -------
__global__ void k_bias(const float* __restrict__ cpb, float* __restrict__ bias) {
  int idx = blockIdx.x * 256 + threadIdx.x;
  if (idx >= HEADS * NPIX * NPIX) return;
  int m = idx % NPIX;
  int n = (idx / NPIX) % NPIX;
  int h = idx / (NPIX * NPIX);
  int sy = (n / WIN - m / WIN) + (WIN - 1);
  int sx = (n % WIN - m % WIN) + (WIN - 1);
  const double inv_log_beta = 1.0 / log(1.3);
  double fy = (sy == 0 ? 0.0 : log1p((double)sy) * inv_log_beta) + 6.0;
  double fx = (sx == 0 ? 0.0 : log1p((double)sx) * inv_log_beta) + 6.0;
  fy = fmin(12.0, fmax(0.0, fy));
  fx = fmin(12.0, fmax(0.0, fx));
  int ridx = (int)(fy * 13.0 + fx);
  bias[idx] = cpb[ridx * HEADS + h] * 1.4426950408889634f;   // * log2(e)
}

__global__ void k_rmap(int* __restrict__ rmap) {
  int p = blockIdx.x * 256 + threadIdx.x;
  if (p < NPF) {
    int wb = p / NPIX, n = p - (p / NPIX) * NPIX;
    int gy = wb >> 3, gx = wb & 7;
    int wy = n / WIN, wx = n - (n / WIN) * WIN;
    rmap[p] = ((gy * WIN + wy + 4) % IMG) * IMG + (gx * WIN + wx + 4) % IMG;
  }
}

// ---------------- weights -> bf16 (once) ----------------
__global__ void k_wcvt(const float* __restrict__ wqkv, const float* __restrict__ wproj,
                       ushort* __restrict__ wqb, ushort* __restrict__ wpb) {
  int i = blockIdx.x * 256 + threadIdx.x;
  const int nq = 1152 * DIM / 8;
  const int np = DIM * DIM / 8;
  if (i < nq) {
    f4 a = *(const f4*)&wqkv[i * 8];
    f4 b = *(const f4*)&wqkv[i * 8 + 4];
    us8 u; u[0]=tob(a[0]);u[1]=tob(a[1]);u[2]=tob(a[2]);u[3]=tob(a[3]);
    u[4]=tob(b[0]);u[5]=tob(b[1]);u[6]=tob(b[2]);u[7]=tob(b[3]);
    *(us8*)&wqb[i * 8] = u;
  } else if (i < nq + np) {
    int j = i - nq;
    f4 a = *(const f4*)&wproj[j * 8];
    f4 b = *(const f4*)&wproj[j * 8 + 4];
    us8 u; u[0]=tob(a[0]);u[1]=tob(a[1]);u[2]=tob(a[2]);u[3]=tob(a[3]);
    u[4]=tob(b[0]);u[5]=tob(b[1]);u[6]=tob(b[2]);u[7]=tob(b[3]);
    *(us8*)&wpb[j * 8] = u;
  }
}

// ---------------- x -> xw[b][p'][c] bf16, 6-way channel-split ---------------
__global__ __launch_bounds__(256) void k_xw(const float* __restrict__ x,
                                            const int* __restrict__ rmap,
                                            ushort* __restrict__ xw) {
  int gid = blockIdx.x * 256 + threadIdx.x;   // 16*6*3136 exact
  int p  = gid % NPF;
  int cc = (gid / NPF) % 6;
  int b  = gid / (6 * NPF);
  int sp = rmap[p];
  const float* xs = x + (size_t)b * DIM * NPF + (size_t)(cc * 64) * NPF + sp;
  ushort* xd = xw + ((size_t)b * NPF + p) * DIM + cc * 64;
  for (int c0 = 0; c0 < 64; c0 += 8) {
    us8 u;
#pragma unroll
    for (int i = 0; i < 8; ++i) u[i] = tob(xs[(size_t)(c0 + i) * NPF]);
    *(us8*)&xd[c0] = u;
  }
}

// ---------------- QKV GEMM: 128x128 tile; q/k -> qk[b][p][768], v -> vt ------
__global__ __launch_bounds__(256) void k_qkv_pm(const ushort* __restrict__ xw,
                                                const ushort* __restrict__ wqb,
                                                ushort* __restrict__ qk,
                                                ushort* __restrict__ vt) {
  __shared__ __align__(16) ushort sA[2][128 * 40];
  __shared__ __align__(16) ushort sB[2][128 * 40];
  int t   = threadIdx.x;
  int bid = blockIdx.x;
  int swz = (bid & 7) * 450 + (bid >> 3);   // 3600 = 8*450, bijective
  int o0  = (swz % 9) * 128;
  int pbt = swz / 9;
  int p0  = (pbt % 25) * 128;
  int b   = pbt / 25;

  int lane = t & 63, w = t >> 6;
  int wm = w >> 1, wn = w & 1;
  int l15 = lane & 15, l4 = lane >> 4;

  int ra0 = t >> 2,          ca0 = (t & 3) * 8;
  int ra1 = (t + 256) >> 2,  ca1 = ((t + 256) & 3) * 8;
  const ushort* apt0 = wqb + (size_t)(o0 + ra0) * DIM + ca0;
  const ushort* apt1 = wqb + (size_t)(o0 + ra1) * DIM + ca1;
  int pr0 = p0 + ra0; if (pr0 >= NPF) pr0 = NPF - 1;
  int pr1 = p0 + ra1; if (pr1 >= NPF) pr1 = NPF - 1;
  const ushort* bpt0 = xw + ((size_t)b * NPF + pr0) * DIM + ca0;
  const ushort* bpt1 = xw + ((size_t)b * NPF + pr1) * DIM + ca1;

  struct Stage { us8 a0, a1, b0, b1; };
  Stage st0, st1;

#define QLOAD(S, K0)                                    \
  do {                                                  \
    (S).a0 = *(const us8*)&apt0[(K0)];                  \
    (S).a1 = *(const us8*)&apt1[(K0)];                  \
    (S).b0 = *(const us8*)&bpt0[(K0)];                  \
    (S).b1 = *(const us8*)&bpt1[(K0)];                  \
  } while (0)
#define QWRITE(S, BUF)                                  \
  do {                                                  \
    *(us8*)&sA[(BUF)][ra0 * 40 + ca0] = (S).a0;         \
    *(us8*)&sA[(BUF)][ra1 * 40 + ca1] = (S).a1;         \
    *(us8*)&sB[(BUF)][ra0 * 40 + ca0] = (S).b0;         \
    *(us8*)&sB[(BUF)][ra1 * 40 + ca1] = (S).b1;         \
  } while (0)

  f32x4 acc[4][4] = {};

  QLOAD(st0, 0);
  QWRITE(st0, 0);
  QLOAD(st1, 32);

#pragma unroll
  for (int ks = 0; ks < 12; ++ks) {
    SOFT_BARRIER();
    if (ks < 10) {
      if ((ks & 1) == 0) QLOAD(st0, (ks + 2) * 32);
      else               QLOAD(st1, (ks + 2) * 32);
    }
    int cur = ks & 1;
    short8 af[4], bfr[4];
#pragma unroll
    for (int mi = 0; mi < 4; ++mi)
      af[mi] = *(const short8*)&sA[cur][(wm * 64 + mi * 16 + l15) * 40 + l4 * 8];
#pragma unroll
    for (int ni = 0; ni < 4; ++ni)
      bfr[ni] = *(const short8*)&sB[cur][(wn * 64 + ni * 16 + l15) * 40 + l4 * 8];
#pragma unroll
    for (int mi = 0; mi < 4; ++mi)
#pragma unroll
      for (int ni = 0; ni < 4; ++ni)
        acc[mi][ni] = MFMA(af[mi], bfr[ni], acc[mi][ni], 0, 0, 0);
    if (ks < 11) {
      if ((ks & 1) == 0) QWRITE(st1, 1);
      else               QWRITE(st0, 0);
    }
  }
#undef QLOAD
#undef QWRITE

  if (o0 < 768) {
#pragma unroll
    for (int mi = 0; mi < 4; ++mi)
#pragma unroll
      for (int ni = 0; ni < 4; ++ni) {
        int p = p0 + wn * 64 + ni * 16 + l15;
        if (p < NPF) {
          us4 u;
#pragma unroll
          for (int r = 0; r < 4; ++r) u[r] = tob(acc[mi][ni][r]);
          *(us4*)&qk[((size_t)b * NPF + p) * 768 + o0 + wm * 64 + mi * 16 + (l4 << 2)] = u;
        }
      }
  } else {
    int c0 = o0 - 768 + wm * 64;
#pragma unroll
    for (int mi = 0; mi < 4; ++mi)
#pragma unroll
      for (int ni = 0; ni < 4; ++ni) {
        int p = p0 + wn * 64 + ni * 16 + l15;
        if (p < NPF) {
#pragma unroll
          for (int r = 0; r < 4; ++r) {
            int c = c0 + mi * 16 + (l4 << 2) + r;
            vt[((size_t)b * DIM + c) * NPF + p] = tob(acc[mi][ni][r]);
          }
        }
      }
  }
}

// ---------------- attention: exp2-softmax, 4 heads/block --------------------
__global__ __launch_bounds__(256) void k_attn_pm(ushort* __restrict__ qk,
                                                 const ushort* __restrict__ vt,
                                                 const float* __restrict__ bias) {
  __shared__ __align__(16) ushort pab[4][64 * 72];   // 36864 B

  int t = threadIdx.x;
  int lane = t & 63, wv = t >> 6;
  int bid = blockIdx.x;
  int swz = (bid & 7) * 384 + (bid >> 3);   // 3072 = 8*384, bijective
  int hg = swz % 3, wb = swz / 3;
  int h = hg * 4 + wv;
  int b = wb >> 6;
  int w49 = (wb & 63) * NPIX;
  ushort* qrow = qk + ((size_t)b * NPF + w49) * 768 + h * HD;
  const ushort* vrow = vt + ((size_t)b * DIM + h * HD) * NPF + w49;
  ushort* pa = pab[wv];

  int l15 = lane & 15, l4 = lane >> 4;

  short8 af[4], bfr[4];
#pragma unroll
  for (int mi = 0; mi < 4; ++mi) {
    int rq = mi * 16 + l15; if (rq > 48) rq = 48;
    af[mi] = *(const short8*)&qrow[(size_t)rq * 768 + l4 * 8];
  }
#pragma unroll
  for (int ni = 0; ni < 4; ++ni) {
    int rk = ni * 16 + l15; if (rk > 48) rk = 48;
    bfr[ni] = *(const short8*)&qrow[(size_t)rk * 768 + DIM + l4 * 8];
  }
  f32x4 acc[4][4] = {};
#pragma unroll
  for (int mi = 0; mi < 4; ++mi)
#pragma unroll
    for (int ni = 0; ni < 4; ++ni)
      acc[mi][ni] = MFMA(af[mi], bfr[ni], acc[mi][ni], 0, 0, 0);

  short8 vf[2][2];
#pragma unroll
  for (int ks = 0; ks < 2; ++ks)
#pragma unroll
    for (int nd = 0; nd < 2; ++nd)
      vf[ks][nd] = *(const short8*)&vrow[(size_t)(nd * 16 + l15) * NPF + ks * 32 + l4 * 8];

  // exp2-softmax: P = exp2(s*c1 + b2) / sum, c1 = scale*log2(e), b2 = b*log2(e)
  const float c1 = 0.25506807186087050f;   // 0.17677669529663687 * 1.4426950408889634
  const float* bh = bias + h * NPIX * NPIX;
  float sm[16];
#pragma unroll
  for (int mi = 0; mi < 4; ++mi)
#pragma unroll
    for (int r = 0; r < 4; ++r) {
      int n = mi * 16 + (l4 << 2) + r;
      float s = 0.f;
#pragma unroll
      for (int ni = 0; ni < 4; ++ni) {
        int m = ni * 16 + l15;
        float e = (m < NPIX && n < NPIX)
                    ? exp2f(fmaf(acc[mi][ni][r], c1, bh[n * NPIX + m]))
                    : 0.f;
        acc[mi][ni][r] = e;
        s += e;
      }
      sm[mi * 4 + r] = s;
    }
#pragma unroll
  for (int i = 1; i < 16; i <<= 1)
#pragma unroll
    for (int j = 0; j < 16; ++j) sm[j] += __shfl_xor(sm[j], i);

#pragma unroll
  for (int mi = 0; mi < 4; ++mi)
#pragma unroll
    for (int r = 0; r < 4; ++r) {
      float ri = 1.f / sm[mi * 4 + r];
      int n = mi * 16 + (l4 << 2) + r;
#pragma unroll
      for (int ni = 0; ni < 4; ++ni)
        pa[n * 72 + ni * 16 + l15] = tob(acc[mi][ni][r] * ri);
    }

  f32x4 yac[4][2] = {};
#pragma unroll
  for (int ks = 0; ks < 2; ++ks) {
    short8 pf[4];
#pragma unroll
    for (int mi = 0; mi < 4; ++mi) pf[mi] = *(const short8*)&pa[(mi * 16 + l15) * 72 + ks * 32 + l4 * 8];
#pragma unroll
    for (int mi = 0; mi < 4; ++mi)
#pragma unroll
      for (int nd = 0; nd < 2; ++nd)
        yac[mi][nd] = MFMA(pf[mi], vf[ks][nd], yac[mi][nd], 0, 0, 0);
  }

#pragma unroll
  for (int mi = 0; mi < 4; ++mi)
#pragma unroll
    for (int nd = 0; nd < 2; ++nd)
#pragma unroll
      for (int r = 0; r < 4; ++r)
        pa[(mi * 16 + (l4 << 2) + r) * 72 + nd * 16 + l15] = tob(yac[mi][nd][r]);
  asm volatile("s_waitcnt lgkmcnt(0)" ::: "memory");
  if (lane < NPIX) {
#pragma unroll
    for (int s = 0; s < 4; ++s)
      *(us8*)&qrow[(size_t)lane * 768 + s * 8] = *(const us8*)&pa[lane * 72 + s * 8];
  }
}

// ---------------- proj GEMM: Y from qk (stride 768) -------------------------
__global__ __launch_bounds__(256) void k_proj_pm(const ushort* __restrict__ qk,
                                                 const ushort* __restrict__ wpb,
                                                 float* __restrict__ out) {
  __shared__ __align__(16) ushort sA[2][128 * 40];
  __shared__ __align__(16) ushort sB[2][128 * 40];
  __shared__ int srm[128];
  int t   = threadIdx.x;
  int bid = blockIdx.x;
  int swz = (bid & 7) * 150 + (bid >> 3);   // 1200 = 8*150
  int o0  = (swz % 3) * 128;
  int pb  = swz / 3;
  int p0  = (pb % 25) * 128;
  int b   = pb / 25;
  if (t < 128) {
    int pg = p0 + t;
    if (pg >= NPF) pg = 0;
    int si = (pg / IMG + 53) % IMG, sj = (pg % IMG + 53) % IMG;
    srm[t] = ((si / WIN) * 8 + sj / WIN) * NPIX + (si % WIN) * WIN + (sj % WIN);
  }
  __syncthreads();

  int lane = t & 63, w = t >> 6;
  int wm = w >> 1, wn = w & 1;
  int l15 = lane & 15, l4 = lane >> 4;

  int ra0 = t >> 2,          ca0 = (t & 3) * 8;
  int ra1 = (t + 256) >> 2,  ca1 = ((t + 256) & 3) * 8;
  const ushort* apt0 = wpb + (size_t)(o0 + ra0) * DIM + ca0;
  const ushort* apt1 = wpb + (size_t)(o0 + ra1) * DIM + ca1;
  const ushort* bpt0 = qk + ((size_t)b * NPF + srm[ra0]) * 768 + ca0;
  const ushort* bpt1 = qk + ((size_t)b * NPF + srm[ra1]) * 768 + ca1;

  struct Stage { us8 a0, a1, b0, b1; };
  Stage st0, st1;

#define PLOAD(S, K0)                                    \
  do {                                                  \
    (S).a0 = *(const us8*)&apt0[(K0)];                  \
    (S).a1 = *(const us8*)&apt1[(K0)];                  \
    (S).b0 = *(const us8*)&bpt0[(K0)];                  \
    (S).b1 = *(const us8*)&bpt1[(K0)];                  \
  } while (0)
#define PWRITE(S, BUF)                                  \
  do {                                                  \
    *(us8*)&sA[(BUF)][ra0 * 40 + ca0] = (S).a0;         \
    *(us8*)&sA[(BUF)][ra1 * 40 + ca1] = (S).a1;         \
    *(us8*)&sB[(BUF)][ra0 * 40 + ca0] = (S).b0;         \
    *(us8*)&sB[(BUF)][ra1 * 40 + ca1] = (S).b1;         \
  } while (0)

  f32x4 acc[4][4] = {};

  PLOAD(st0, 0);
  PWRITE(st0, 0);
  PLOAD(st1, 32);

#pragma unroll
  for (int ks = 0; ks < 12; ++ks) {
    SOFT_BARRIER();
    if (ks < 10) {
      if ((ks & 1) == 0) PLOAD(st0, (ks + 2) * 32);
      else               PLOAD(st1, (ks + 2) * 32);
    }
    int cur = ks & 1;
    short8 af[4], bfr[4];
#pragma unroll
    for (int mi = 0; mi < 4; ++mi)
      af[mi] = *(const short8*)&sA[cur][(wm * 64 + mi * 16 + l15) * 40 + l4 * 8];
#pragma unroll
    for (int ni = 0; ni < 4; ++ni)
      bfr[ni] = *(const short8*)&sB[cur][(wn * 64 + ni * 16 + l15) * 40 + l4 * 8];
#pragma unroll
    for (int mi = 0; mi < 4; ++mi)
#pragma unroll
      for (int ni = 0; ni < 4; ++ni)
        acc[mi][ni] = MFMA(af[mi], bfr[ni], acc[mi][ni], 0, 0, 0);
    if (ks < 11) {
      if ((ks & 1) == 0) PWRITE(st1, 1);
      else               PWRITE(st0, 0);
    }
  }
#undef PLOAD
#undef PWRITE

  for (int mi = 0; mi < 4; ++mi)
    for (int ni = 0; ni < 4; ++ni)
      for (int r = 0; r < 4; ++r) {
        int o = o0 + wm * 64 + mi * 16 + (l4 << 2) + r;
        int p = p0 + wn * 64 + ni * 16 + l15;
        if (p < NPF)
          out[((size_t)b * DIM + o) * NPF + p] = acc[mi][ni][r];
      }
}

extern "C" void kernel_launch(void* const* d_in, const int* in_sizes, int n_in,
                              void* d_out, int out_size, void* d_ws, size_t ws_size,
                              hipStream_t stream) {
  const float* x     = (const float*)d_in[0];
  const float* wqkv  = (const float*)d_in[1];
  const float* wproj = (const float*)d_in[2];
  const float* cpb   = (const float*)d_in[3];
  float* out = (float*)d_out;

  char* ws = (char*)d_ws;
  float* bias = (float*)ws;                       // 115248 B
  int*   rmap = (int*)(ws + 115712);              // -> 131072
  ushort* wqb = (ushort*)(ws + 131072);           // 884736 B
  ushort* wpb = (ushort*)(ws + 1015808);          // 294912 B -> 1310720
  const size_t QK_B = (size_t)16 * NPF * 768 * 2; // 77,070,336
  const size_t VT_B = (size_t)16 * DIM * NPF * 2; // 38,535,168
  ushort* qk = (ushort*)(ws + 1310720);
  ushort* vt = (ushort*)(ws + 1310720 + QK_B);
  ushort* xw = (ushort*)(ws + 1310720 + QK_B + VT_B);  // ends 155,451,392 (proven)

  hipLaunchKernelGGL(k_bias, dim3(113), dim3(256), 0, stream, cpb, bias);
  hipLaunchKernelGGL(k_rmap, dim3(13), dim3(256), 0, stream, rmap);
  hipLaunchKernelGGL(k_wcvt, dim3(288), dim3(256), 0, stream, wqkv, wproj, wqb, wpb);
  hipLaunchKernelGGL(k_xw, dim3(1176), dim3(256), 0, stream, x, rmap, xw);
  hipLaunchKernelGGL(k_qkv_pm, dim3(3600), dim3(256), 0, stream, xw, wqb, qk, vt);
  hipLaunchKernelGGL(k_attn_pm, dim3(3072), dim3(256), 0, stream, qk, vt, bias);
  hipLaunchKernelGGL(k_proj_pm, dim3(1200), dim3(256), 0, stream, qk, wpb, out);
}